// Round 9
// baseline (15596.712 us; speedup 1.0000x reference)
//
#include <hip/hip_runtime.h>

// B=128, T=512, I=256, H=512, O=256. GRU (r,z,n), 2 layers sharing one hidden
// state (quirk), y_t = h @ W_out^T + b_out.
//
// Round 9: round-5 data path (PROVEN PASS: MALL-direct sc0|sc1 h-exchange,
// register f32 carries, 64 blocks, y on waves 0-1) + new RMW-FREE barrier:
//  - arrival: each block sc-STOREs monotonic value (t+1) to its OWN flag word
//    (64 words across 4 lines -> no single-line RMW serialization).
//  - wait: wave 0's lanes 0..15 poll all 64 flags with dwordx4 sc-loads,
//    __all() reduce. No lead block, no go word, no atomics anywhere.
//  - monotonic flags: no per-event arrays, no reset, no reuse hazard;
//    deadlock-free (64 co-resident blocks, values only grow).

typedef short s16x8 __attribute__((ext_vector_type(8)));  // 8 bf16
typedef float f32x4 __attribute__((ext_vector_type(4)));
typedef unsigned int u32x4 __attribute__((ext_vector_type(4)));
typedef unsigned short u16;
typedef unsigned int u32;

#define MFMA(a, b, c) __builtin_amdgcn_mfma_f32_16x16x32_bf16((a), (b), (c), 0, 0, 0)

static constexpr int NBLK = 64;

__device__ __forceinline__ u16 f2bf(float f) {
  unsigned u = __builtin_bit_cast(unsigned, f);
  u = u + 0x7fffu + ((u >> 16) & 1u);
  return (u16)(u >> 16);
}
__device__ __forceinline__ float sigm(float x) { return 1.f / (1.f + __expf(-x)); }
__device__ __forceinline__ float tanh_f(float x) { return 1.f - 2.f / (1.f + __expf(2.f * x)); }

// ---- MALL-direct helpers (round-5-proven semantics) ----
__device__ __forceinline__ s16x8 scload16(const u16* p) {
  s16x8 v;
  asm volatile("global_load_dwordx4 %0, %1, off sc0 sc1" : "=v"(v) : "v"(p));
  return v;  // valid only after VWAIT0()
}
__device__ __forceinline__ void scstore_u16(u16* p, u16 v) {
  unsigned vv = v;
  asm volatile("global_store_short %0, %1, off sc0 sc1" :: "v"(p), "v"(vv) : "memory");
}
__device__ __forceinline__ void scstore_f32(float* p, float v) {
  asm volatile("global_store_dword %0, %1, off sc0 sc1" :: "v"(p), "v"(v) : "memory");
}
#define VWAIT0()                                        \
  do {                                                  \
    asm volatile("s_waitcnt vmcnt(0)" ::: "memory");    \
    __builtin_amdgcn_sched_barrier(0);                  \
  } while (0)

// RMW-free grid barrier. flags[64] monotonic; pass when all >= val.
__device__ __forceinline__ void flagbar(u32* flags, u32 val) {
  asm volatile("s_waitcnt vmcnt(0)" ::: "memory");  // data stores at MALL
  __syncthreads();
  if (threadIdx.x < 64) {                            // wave 0 handles the wait
    if (threadIdx.x == 0) {
      const u32* pme = flags + blockIdx.x;
      asm volatile("global_store_dword %0, %1, off sc0 sc1"
                   :: "v"(pme), "v"(val) : "memory");
      asm volatile("s_waitcnt vmcnt(0)" ::: "memory");
    }
    const u32* p = flags + (threadIdx.x & 15) * 4;
    int ok;
    do {
      __builtin_amdgcn_s_sleep(1);
      ok = 1;
      if (threadIdx.x < 16) {
        u32x4 v;
        asm volatile("global_load_dwordx4 %0, %1, off sc0 sc1\n\ts_waitcnt vmcnt(0)"
                     : "=v"(v) : "v"(p) : "memory");
        u32 m = v.x < v.y ? v.x : v.y;
        u32 m2 = v.z < v.w ? v.z : v.w;
        m = m < m2 ? m : m2;
        ok = (m >= val) ? 1 : 0;
      }
    } while (!__all(ok));
  }
  __syncthreads();
}

// ---------------- weight prep + flag zeroing (once per call) ----------------
__global__ void prep_kernel(const float* __restrict__ W_ih0, const float* __restrict__ W_hh0,
                            const float* __restrict__ W_ih1, const float* __restrict__ W_hh1,
                            const float* __restrict__ W_out, const float* __restrict__ h0,
                            u16* __restrict__ WL0, u16* __restrict__ WL1,
                            u16* __restrict__ WOB, u16* __restrict__ HbB0,
                            u32* __restrict__ flags) {
  const int n0 = 1536 * 768, n1 = 2048 * 512, n2 = 256 * 512, n3 = 128 * 512, n4 = 128;
  const int total = n0 + n1 + n2 + n3 + n4;
  for (int i = blockIdx.x * blockDim.x + threadIdx.x; i < total; i += gridDim.x * blockDim.x) {
    if (i < n0) {
      int row = i / 768, c = i % 768;
      float v = (c < 256) ? W_ih0[row * 256 + c] : W_hh0[row * 512 + (c - 256)];
      WL0[i] = f2bf(v);
    } else if (i < n0 + n1) {
      int k2 = i - n0;
      int row = k2 / 512, k = k2 % 512;
      int strip = row >> 9, j = row & 511;
      float v;
      if (strip == 0)      v = W_ih1[j * 512 + k] + W_hh1[j * 512 + k];
      else if (strip == 1) v = W_ih1[(512 + j) * 512 + k] + W_hh1[(512 + j) * 512 + k];
      else if (strip == 2) v = W_ih1[(1024 + j) * 512 + k];
      else                 v = W_hh1[(1024 + j) * 512 + k];
      WL1[k2] = f2bf(v);
    } else if (i < n0 + n1 + n2) {
      int k2 = i - n0 - n1;
      WOB[k2] = f2bf(W_out[k2]);
    } else if (i < n0 + n1 + n2 + n3) {
      int k2 = i - n0 - n1 - n2;
      HbB0[k2] = f2bf(h0[k2]);
    } else {
      flags[i - n0 - n1 - n2 - n3] = 0u;
    }
  }
}

// ---------------- persistent GRU kernel (64 blocks) ----------------
__global__ __launch_bounds__(256) void gru_persist(
    const float* __restrict__ x, const float* __restrict__ h0,
    const float* __restrict__ b_ih0, const float* __restrict__ b_hh0,
    const float* __restrict__ b_ih1, const float* __restrict__ b_hh1,
    const float* __restrict__ b_out,
    const u16* __restrict__ WL0, const u16* __restrict__ WL1, const u16* __restrict__ WOB,
    u16* __restrict__ HbB0, u16* __restrict__ HbB1, u16* __restrict__ hLB,
    float* __restrict__ Y, u32* __restrict__ flagsA, u32* __restrict__ flagsB) {
  const int blk = blockIdx.x;
  const int w = threadIdx.x >> 6, l = threadIdx.x & 63;
  const int l15 = l & 15, l4 = l >> 4;

  // ---- L0/L1 task mapping (round-5-proven) ----
  const int cg = blk & 31;                 // 16 hidden cols
  const int mt = (blk >> 5) * 4 + w;       // m-tile 0..7 (16 batch rows)
  const int brow = mt * 16 + l15;
  const int jg = cg * 16 + l15;
  const int b0 = mt * 16 + l4 * 4;
  const u16* wr  = WL0 + (size_t)jg * 768 + l4 * 8;
  const u16* wz  = WL0 + (size_t)(512 + jg) * 768 + l4 * 8;
  const u16* wn  = WL0 + (size_t)(1024 + jg) * 768 + l4 * 8;
  const u16* w10 = WL1 + (size_t)jg * 512 + l4 * 8;   // r (pre-summed)
  const u16* w11 = w10 + 512 * 512;                   // z (pre-summed)
  const u16* w12 = w10 + 1024 * 512;                  // i_n
  const u16* w13 = w10 + 1536 * 512;                  // h_n
  const float br0 = b_ih0[jg] + b_hh0[jg];
  const float bz0 = b_ih0[512 + jg] + b_hh0[512 + jg];
  const float bni0 = b_ih0[1024 + jg], bnh0 = b_hh0[1024 + jg];
  const float br1 = b_ih1[jg] + b_hh1[jg];
  const float bz1 = b_ih1[512 + jg] + b_hh1[512 + jg];
  const float bni1 = b_ih1[1024 + jg], bnh1 = b_hh1[1024 + jg];
  const float* xrow = x + (size_t)brow * 512 * 256 + l4 * 8;

  // ---- register f32 carries ----
  float hreg[4], hl[4];
  #pragma unroll
  for (int j = 0; j < 4; ++j) hreg[j] = h0[(size_t)(b0 + j) * 512 + jg];

  // ---- y-tile mapping: waves 0-1 own one of 128 tiles ----
  const int yid = blk * 2 + w;             // valid when w < 2
  const int ymt = yid & 7, ynt = yid >> 3;
  const int yo = ynt * 16 + l15;
  const float ybo = b_out[yo & 255];
  const u16* ywv = WOB + (size_t)(yo & 255) * 512 + l4 * 8;
  const int yarow = (ymt * 16 + l15) * 512 + l4 * 8;
  const int yb0 = ymt * 16 + l4 * 4;

  for (int t = 0; t < 512; ++t) {
    u16* HbBc = (t & 1) ? HbB1 : HbB0;     // h(t-1), bf16
    u16* HbBn = (t & 1) ? HbB0 : HbB1;     // h(t) dest

    // ---- y(t-1): waves 0-1, reads HbBc via MALL ----
    if (w < 2 && t > 0) {
      s16x8 yb[16];
      const u16* ar = HbBc + yarow;
      #pragma unroll
      for (int kt = 0; kt < 16; ++kt) yb[kt] = scload16(ar + kt * 32);
      VWAIT0();
      f32x4 acc = {0, 0, 0, 0};
      #pragma unroll
      for (int kt = 0; kt < 16; ++kt)
        acc = MFMA(yb[kt], *(const s16x8*)(ywv + kt * 32), acc);
      #pragma unroll
      for (int j = 0; j < 4; ++j)
        scstore_f32(&Y[((size_t)(yb0 + j) * 512 + (t - 1)) * 256 + yo], acc[j] + ybo);
    }

    // ---- phase A: layer 0 (h loads issued first to hide MALL latency) ----
    s16x8 hb[16];
    {
      const u16* hr = HbBc + (size_t)brow * 512 + l4 * 8;
      #pragma unroll
      for (int kt = 0; kt < 16; ++kt) hb[kt] = scload16(hr + kt * 32);
    }
    f32x4 aR = {0,0,0,0}, aZ = {0,0,0,0}, aNI = {0,0,0,0}, aNH = {0,0,0,0};
    const float* xr = xrow + (size_t)t * 256;
    #pragma unroll
    for (int kt = 0; kt < 8; ++kt) {
      float4 u = *(const float4*)(xr + kt * 32);
      float4 v = *(const float4*)(xr + kt * 32 + 4);
      s16x8 a;
      a[0] = f2bf(u.x); a[1] = f2bf(u.y); a[2] = f2bf(u.z); a[3] = f2bf(u.w);
      a[4] = f2bf(v.x); a[5] = f2bf(v.y); a[6] = f2bf(v.z); a[7] = f2bf(v.w);
      aR  = MFMA(a, *(const s16x8*)(wr + kt * 32), aR);
      aZ  = MFMA(a, *(const s16x8*)(wz + kt * 32), aZ);
      aNI = MFMA(a, *(const s16x8*)(wn + kt * 32), aNI);
    }
    VWAIT0();
    #pragma unroll
    for (int kt = 0; kt < 16; ++kt) {
      aR  = MFMA(hb[kt], *(const s16x8*)(wr + (8 + kt) * 32), aR);
      aZ  = MFMA(hb[kt], *(const s16x8*)(wz + (8 + kt) * 32), aZ);
      aNH = MFMA(hb[kt], *(const s16x8*)(wn + (8 + kt) * 32), aNH);
    }
    #pragma unroll
    for (int j = 0; j < 4; ++j) {
      float r = sigm(aR[j] + br0);
      float z = sigm(aZ[j] + bz0);
      float n = tanh_f(aNI[j] + bni0 + r * (aNH[j] + bnh0));
      float h = (1.f - z) * n + z * hreg[j];
      hl[j] = h;
      scstore_u16(&hLB[(size_t)(b0 + j) * 512 + jg], f2bf(h));
    }
    flagbar(flagsA, (u32)(t + 1));

    // ---- phase B: layer 1 (input == hidden == h_l0) ----
    f32x4 cR = {0,0,0,0}, cZ = {0,0,0,0}, cNI = {0,0,0,0}, cNH = {0,0,0,0};
    {
      s16x8 pb[16];
      const u16* ar = hLB + (size_t)brow * 512 + l4 * 8;
      #pragma unroll
      for (int kt = 0; kt < 16; ++kt) pb[kt] = scload16(ar + kt * 32);
      VWAIT0();
      #pragma unroll
      for (int kt = 0; kt < 16; ++kt) {
        cR  = MFMA(pb[kt], *(const s16x8*)(w10 + kt * 32), cR);
        cZ  = MFMA(pb[kt], *(const s16x8*)(w11 + kt * 32), cZ);
        cNI = MFMA(pb[kt], *(const s16x8*)(w12 + kt * 32), cNI);
        cNH = MFMA(pb[kt], *(const s16x8*)(w13 + kt * 32), cNH);
      }
    }
    #pragma unroll
    for (int j = 0; j < 4; ++j) {
      float r = sigm(cR[j] + br1);
      float z = sigm(cZ[j] + bz1);
      float n = tanh_f(cNI[j] + bni1 + r * (cNH[j] + bnh1));
      float h = (1.f - z) * n + z * hl[j];
      hreg[j] = h;
      scstore_u16(&HbBn[(size_t)(b0 + j) * 512 + jg], f2bf(h));
    }
    flagbar(flagsB, (u32)(t + 1));
  }

  // ---- final y (t = 511): state after step 511 is in buffer 0 ----
  if (w < 2) {
    s16x8 yb[16];
    const u16* ar = HbB0 + yarow;
    #pragma unroll
    for (int kt = 0; kt < 16; ++kt) yb[kt] = scload16(ar + kt * 32);
    VWAIT0();
    f32x4 acc = {0, 0, 0, 0};
    #pragma unroll
    for (int kt = 0; kt < 16; ++kt)
      acc = MFMA(yb[kt], *(const s16x8*)(ywv + kt * 32), acc);
    #pragma unroll
    for (int j = 0; j < 4; ++j)
      scstore_f32(&Y[((size_t)(yb0 + j) * 512 + 511) * 256 + yo], acc[j] + ybo);
  }
}

extern "C" void kernel_launch(void* const* d_in, const int* in_sizes, int n_in,
                              void* d_out, int out_size, void* d_ws, size_t ws_size,
                              hipStream_t stream) {
  const float* x     = (const float*)d_in[0];
  const float* h0    = (const float*)d_in[1];
  const float* W_ih0 = (const float*)d_in[2];
  const float* W_hh0 = (const float*)d_in[3];
  const float* b_ih0 = (const float*)d_in[4];
  const float* b_hh0 = (const float*)d_in[5];
  const float* W_ih1 = (const float*)d_in[6];
  const float* W_hh1 = (const float*)d_in[7];
  const float* b_ih1 = (const float*)d_in[8];
  const float* b_hh1 = (const float*)d_in[9];
  const float* W_out = (const float*)d_in[10];
  const float* b_out = (const float*)d_in[11];
  float* Y = (float*)d_out;

  // ws carve: flags first (512 B), then bf16 data (~5.3 MiB)
  u32* flagsA = (u32*)d_ws;           // 64 u32
  u32* flagsB = flagsA + 64;          // 64 u32
  u16* WL0  = (u16*)(flagsA + 128);   // 1536*768
  u16* WL1  = WL0 + 1536 * 768;       // 2048*512
  u16* WOB  = WL1 + 2048 * 512;       // 256*512
  u16* HbB0 = WOB + 256 * 512;        // 128*512
  u16* HbB1 = HbB0 + 128 * 512;
  u16* hLB  = HbB1 + 128 * 512;

  prep_kernel<<<dim3(1024), dim3(256), 0, stream>>>(W_ih0, W_hh0, W_ih1, W_hh1,
                                                    W_out, h0, WL0, WL1, WOB,
                                                    HbB0, flagsA);
  gru_persist<<<dim3(NBLK), dim3(256), 0, stream>>>(
      x, h0, b_ih0, b_hh0, b_ih1, b_hh1, b_out, WL0, WL1, WOB,
      HbB0, HbB1, hLB, Y, flagsA, flagsB);
}

// Round 11
// 14611.028 us; speedup vs baseline: 1.0675x; 1.0675x over previous
//
#include <hip/hip_runtime.h>

// B=128, T=512, I=256, H=512, O=256. GRU (r,z,n), 2 layers sharing one hidden
// state (quirk), y_t = h @ W_out^T + b_out.
//
// Round 11: round-5 PROVEN structure (64 real blocks x 256 thr, MALL sc0|sc1
// data path, RMW+go barrier, register f32 carries) with two changes:
//  1. +160 HEATER blocks: dense FMA loops keep DPM clocks boosted (theory:
//     the universal ~30us/step across sync mechanisms = idle-downclocking).
//     Heaters write nothing, poll a done flag (~every 3us), hard-capped.
//  2. y(t-1) fused into phase A on even-cg waves, reusing the hb registers
//     (h(t-1) already loaded for the gates) -> zero extra loads for y.

typedef short s16x8 __attribute__((ext_vector_type(8)));  // 8 bf16
typedef float f32x4 __attribute__((ext_vector_type(4)));
typedef unsigned short u16;
typedef unsigned int u32;

#define MFMA(a, b, c) __builtin_amdgcn_mfma_f32_16x16x32_bf16((a), (b), (c), 0, 0, 0)

static constexpr int NREAL = 64;    // barrier participants
static constexpr int NHEAT = 160;
static constexpr int NALL  = 224;
static constexpr int HEAT_CAP = 30000;
static constexpr int BAR_U32 = 65552;  // 1024 events * 64 u32 + done line

__device__ __forceinline__ u16 f2bf(float f) {
  unsigned u = __builtin_bit_cast(unsigned, f);
  u = u + 0x7fffu + ((u >> 16) & 1u);
  return (u16)(u >> 16);
}
__device__ __forceinline__ float sigm(float x) { return 1.f / (1.f + __expf(-x)); }
__device__ __forceinline__ float tanh_f(float x) { return 1.f - 2.f / (1.f + __expf(2.f * x)); }

// ---- MALL-direct helpers (round-5-proven semantics) ----
__device__ __forceinline__ s16x8 scload16(const u16* p) {
  s16x8 v;
  asm volatile("global_load_dwordx4 %0, %1, off sc0 sc1" : "=v"(v) : "v"(p));
  return v;  // valid only after VWAIT0()
}
__device__ __forceinline__ void scstore_u16(u16* p, u16 v) {
  unsigned vv = v;
  asm volatile("global_store_short %0, %1, off sc0 sc1" :: "v"(p), "v"(vv) : "memory");
}
#define VWAIT0()                                        \
  do {                                                  \
    asm volatile("s_waitcnt vmcnt(0)" ::: "memory");    \
    __builtin_amdgcn_sched_barrier(0);                  \
  } while (0)

// Grid barrier over NREAL blocks (round-5-proven, byte-identical semantics).
// Event layout: ctr at +0, go word at +32 (separate 128B line).
__device__ __forceinline__ void gbar(u32* ev, bool lead) {
  asm volatile("s_waitcnt vmcnt(0)" ::: "memory");  // drain sc-stores to MALL
  __syncthreads();
  if (threadIdx.x == 0) {
    __hip_atomic_fetch_add(ev, 1u, __ATOMIC_RELAXED, __HIP_MEMORY_SCOPE_AGENT);
    if (lead) {
      while (__hip_atomic_fetch_add(ev, 0u, __ATOMIC_RELAXED, __HIP_MEMORY_SCOPE_AGENT)
             < (unsigned)NREAL) {
        __builtin_amdgcn_s_sleep(2);
      }
      unsigned one = 1u;
      asm volatile("global_store_dword %0, %1, off sc0 sc1" :: "v"(ev + 32), "v"(one) : "memory");
    } else {
      unsigned g = 0;
      do {
        __builtin_amdgcn_s_sleep(4);
        asm volatile("global_load_dword %0, %1, off sc0 sc1\n\ts_waitcnt vmcnt(0)"
                     : "=v"(g) : "v"(ev + 32) : "memory");
      } while (g == 0);
    }
  }
  __syncthreads();
}

// ---------------- weight prep + barrier reset (once per call) ----------------
__global__ void prep_kernel(const float* __restrict__ W_ih0, const float* __restrict__ W_hh0,
                            const float* __restrict__ W_ih1, const float* __restrict__ W_hh1,
                            const float* __restrict__ W_out, const float* __restrict__ h0,
                            u16* __restrict__ WL0, u16* __restrict__ WL1,
                            u16* __restrict__ WOB, u16* __restrict__ HbB0,
                            u32* __restrict__ bar) {
  const int n0 = 1536 * 768, n1 = 2048 * 512, n2 = 256 * 512, n3 = 128 * 512;
  const int total = n0 + n1 + n2 + n3 + BAR_U32;
  for (int i = blockIdx.x * blockDim.x + threadIdx.x; i < total; i += gridDim.x * blockDim.x) {
    if (i < n0) {
      int row = i / 768, c = i % 768;
      float v = (c < 256) ? W_ih0[row * 256 + c] : W_hh0[row * 512 + (c - 256)];
      WL0[i] = f2bf(v);
    } else if (i < n0 + n1) {
      int k2 = i - n0;
      int row = k2 / 512, k = k2 % 512;
      int strip = row >> 9, j = row & 511;
      float v;
      if (strip == 0)      v = W_ih1[j * 512 + k] + W_hh1[j * 512 + k];
      else if (strip == 1) v = W_ih1[(512 + j) * 512 + k] + W_hh1[(512 + j) * 512 + k];
      else if (strip == 2) v = W_ih1[(1024 + j) * 512 + k];
      else                 v = W_hh1[(1024 + j) * 512 + k];
      WL1[k2] = f2bf(v);
    } else if (i < n0 + n1 + n2) {
      int k2 = i - n0 - n1;
      WOB[k2] = f2bf(W_out[k2]);
    } else if (i < n0 + n1 + n2 + n3) {
      int k2 = i - n0 - n1 - n2;
      HbB0[k2] = f2bf(h0[k2]);
    } else {
      bar[i - n0 - n1 - n2 - n3] = 0u;
    }
  }
}

// ---------------- persistent GRU kernel (64 real + 160 heater blocks) --------
__global__ __launch_bounds__(256) void gru_persist(
    const float* __restrict__ x, const float* __restrict__ h0,
    const float* __restrict__ b_ih0, const float* __restrict__ b_hh0,
    const float* __restrict__ b_ih1, const float* __restrict__ b_hh1,
    const float* __restrict__ b_out,
    const u16* __restrict__ WL0, const u16* __restrict__ WL1, const u16* __restrict__ WOB,
    u16* __restrict__ HbB0, u16* __restrict__ HbB1, u16* __restrict__ hLB,
    float* __restrict__ Y, u32* __restrict__ bar) {
  const int blk = blockIdx.x;
  u32* done = bar + 65536;

  if (blk >= NREAL) {
    // ---- heater: dense VALU to keep DPM clocks boosted. Writes nothing. ----
    float a0 = 1.0f + threadIdx.x * 1e-6f, a1 = 1.1f, a2 = 1.2f, a3 = 1.3f;
    float a4 = 1.4f, a5 = 1.5f, a6 = 1.6f, a7 = 1.7f;
    for (int it = 0; it < HEAT_CAP; ++it) {
      #pragma unroll 32
      for (int k = 0; k < 2048; ++k) {
        a0 = __builtin_fmaf(a0, 0.9999999f, 1e-9f);
        a1 = __builtin_fmaf(a1, 0.9999999f, 1e-9f);
        a2 = __builtin_fmaf(a2, 0.9999999f, 1e-9f);
        a3 = __builtin_fmaf(a3, 0.9999999f, 1e-9f);
        a4 = __builtin_fmaf(a4, 0.9999999f, 1e-9f);
        a5 = __builtin_fmaf(a5, 0.9999999f, 1e-9f);
        a6 = __builtin_fmaf(a6, 0.9999999f, 1e-9f);
        a7 = __builtin_fmaf(a7, 0.9999999f, 1e-9f);
      }
      u32 d;
      asm volatile("global_load_dword %0, %1, off sc0 sc1\n\ts_waitcnt vmcnt(0)"
                   : "=v"(d) : "v"((const u32*)done) : "memory");
      if (d) break;
    }
    asm volatile("" :: "v"(a0), "v"(a1), "v"(a2), "v"(a3),
                       "v"(a4), "v"(a5), "v"(a6), "v"(a7));
    return;
  }

  const bool lead = (blk == 0);
  const int w = threadIdx.x >> 6, l = threadIdx.x & 63;
  const int l15 = l & 15, l4 = l >> 4;

  // ---- L0/L1 task mapping (round-5-proven) ----
  const int cg = blk & 31;                 // 16 hidden cols
  const int mt = (blk >> 5) * 4 + w;       // m-tile 0..7 (16 batch rows)
  const int brow = mt * 16 + l15;
  const int jg = cg * 16 + l15;
  const int b0 = mt * 16 + l4 * 4;
  const u16* wr  = WL0 + (size_t)jg * 768 + l4 * 8;
  const u16* wz  = WL0 + (size_t)(512 + jg) * 768 + l4 * 8;
  const u16* wn  = WL0 + (size_t)(1024 + jg) * 768 + l4 * 8;
  const u16* w10 = WL1 + (size_t)jg * 512 + l4 * 8;   // r (pre-summed)
  const u16* w11 = w10 + 512 * 512;                   // z (pre-summed)
  const u16* w12 = w10 + 1024 * 512;                  // i_n
  const u16* w13 = w10 + 1536 * 512;                  // h_n
  const float br0 = b_ih0[jg] + b_hh0[jg];
  const float bz0 = b_ih0[512 + jg] + b_hh0[512 + jg];
  const float bni0 = b_ih0[1024 + jg], bnh0 = b_hh0[1024 + jg];
  const float br1 = b_ih1[jg] + b_hh1[jg];
  const float bz1 = b_ih1[512 + jg] + b_hh1[512 + jg];
  const float bni1 = b_ih1[1024 + jg], bnh1 = b_hh1[1024 + jg];
  const float* xrow = x + (size_t)brow * 512 * 256 + l4 * 8;

  // ---- register f32 carries ----
  float hreg[4], hl[4];
  #pragma unroll
  for (int j = 0; j < 4; ++j) hreg[j] = h0[(size_t)(b0 + j) * 512 + jg];

  // ---- fused y mapping: even-cg waves own tile (mt, ynt = cg/2) ----
  const bool ywave = ((cg & 1) == 0);
  const int yo = (cg >> 1) * 16 + l15;     // output col 0..255
  const float ybo = b_out[yo];
  const u16* ywv = WOB + (size_t)yo * 512 + l4 * 8;

  for (int t = 0; t < 512; ++t) {
    u16* HbBc = (t & 1) ? HbB1 : HbB0;     // h(t-1), bf16
    u16* HbBn = (t & 1) ? HbB0 : HbB1;     // h(t) dest

    // ---- phase A: issue h(t-1) loads first (hide MALL latency under x) ----
    s16x8 hb[16];
    {
      const u16* hr = HbBc + (size_t)brow * 512 + l4 * 8;
      #pragma unroll
      for (int kt = 0; kt < 16; ++kt) hb[kt] = scload16(hr + kt * 32);
    }
    f32x4 aR = {0,0,0,0}, aZ = {0,0,0,0}, aNI = {0,0,0,0}, aNH = {0,0,0,0};
    const float* xr = xrow + (size_t)t * 256;
    #pragma unroll
    for (int kt = 0; kt < 8; ++kt) {
      float4 u = *(const float4*)(xr + kt * 32);
      float4 v = *(const float4*)(xr + kt * 32 + 4);
      s16x8 a;
      a[0] = f2bf(u.x); a[1] = f2bf(u.y); a[2] = f2bf(u.z); a[3] = f2bf(u.w);
      a[4] = f2bf(v.x); a[5] = f2bf(v.y); a[6] = f2bf(v.z); a[7] = f2bf(v.w);
      aR  = MFMA(a, *(const s16x8*)(wr + kt * 32), aR);
      aZ  = MFMA(a, *(const s16x8*)(wz + kt * 32), aZ);
      aNI = MFMA(a, *(const s16x8*)(wn + kt * 32), aNI);
    }
    VWAIT0();
    #pragma unroll
    for (int kt = 0; kt < 16; ++kt) {
      aR  = MFMA(hb[kt], *(const s16x8*)(wr + (8 + kt) * 32), aR);
      aZ  = MFMA(hb[kt], *(const s16x8*)(wz + (8 + kt) * 32), aZ);
      aNH = MFMA(hb[kt], *(const s16x8*)(wn + (8 + kt) * 32), aNH);
    }

    // ---- fused y(t-1): reuse hb registers (zero extra loads) ----
    if (ywave && t > 0) {
      f32x4 acc = {0,0,0,0};
      #pragma unroll
      for (int kt = 0; kt < 16; ++kt)
        acc = MFMA(hb[kt], *(const s16x8*)(ywv + kt * 32), acc);
      #pragma unroll
      for (int j = 0; j < 4; ++j)
        Y[((size_t)(b0 + j) * 512 + (t - 1)) * 256 + yo] = acc[j] + ybo;
    }

    // ---- L0 epilogue ----
    #pragma unroll
    for (int j = 0; j < 4; ++j) {
      float r = sigm(aR[j] + br0);
      float z = sigm(aZ[j] + bz0);
      float n = tanh_f(aNI[j] + bni0 + r * (aNH[j] + bnh0));
      float h = (1.f - z) * n + z * hreg[j];
      hl[j] = h;
      scstore_u16(&hLB[(size_t)(b0 + j) * 512 + jg], f2bf(h));
    }
    gbar(bar + (size_t)(2 * t) * 64, lead);

    // ---- phase B: layer 1 (input == hidden == h_l0) ----
    f32x4 cR = {0,0,0,0}, cZ = {0,0,0,0}, cNI = {0,0,0,0}, cNH = {0,0,0,0};
    {
      s16x8 pb[16];
      const u16* ar = hLB + (size_t)brow * 512 + l4 * 8;
      #pragma unroll
      for (int kt = 0; kt < 16; ++kt) pb[kt] = scload16(ar + kt * 32);
      VWAIT0();
      #pragma unroll
      for (int kt = 0; kt < 16; ++kt) {
        cR  = MFMA(pb[kt], *(const s16x8*)(w10 + kt * 32), cR);
        cZ  = MFMA(pb[kt], *(const s16x8*)(w11 + kt * 32), cZ);
        cNI = MFMA(pb[kt], *(const s16x8*)(w12 + kt * 32), cNI);
        cNH = MFMA(pb[kt], *(const s16x8*)(w13 + kt * 32), cNH);
      }
    }
    #pragma unroll
    for (int j = 0; j < 4; ++j) {
      float r = sigm(cR[j] + br1);
      float z = sigm(cZ[j] + bz1);
      float n = tanh_f(cNI[j] + bni1 + r * (cNH[j] + bnh1));
      float h = (1.f - z) * n + z * hl[j];
      hreg[j] = h;
      scstore_u16(&HbBn[(size_t)(b0 + j) * 512 + jg], f2bf(h));
    }
    gbar(bar + (size_t)(2 * t + 1) * 64, lead);
  }

  // ---- stop heaters (all real blocks are past the last barrier) ----
  if (lead && threadIdx.x == 0) {
    unsigned one = 1u;
    asm volatile("global_store_dword %0, %1, off sc0 sc1" :: "v"(done), "v"(one) : "memory");
  }

  // ---- final y (t = 511): h(511) is in buffer 0 ----
  if (ywave) {
    s16x8 yb[16];
    const u16* ar = HbB0 + (size_t)brow * 512 + l4 * 8;
    #pragma unroll
    for (int kt = 0; kt < 16; ++kt) yb[kt] = scload16(ar + kt * 32);
    VWAIT0();
    f32x4 acc = {0,0,0,0};
    #pragma unroll
    for (int kt = 0; kt < 16; ++kt)
      acc = MFMA(yb[kt], *(const s16x8*)(ywv + kt * 32), acc);
    #pragma unroll
    for (int j = 0; j < 4; ++j)
      Y[((size_t)(b0 + j) * 512 + 511) * 256 + yo] = acc[j] + ybo;
  }
}

extern "C" void kernel_launch(void* const* d_in, const int* in_sizes, int n_in,
                              void* d_out, int out_size, void* d_ws, size_t ws_size,
                              hipStream_t stream) {
  const float* x     = (const float*)d_in[0];
  const float* h0    = (const float*)d_in[1];
  const float* W_ih0 = (const float*)d_in[2];
  const float* W_hh0 = (const float*)d_in[3];
  const float* b_ih0 = (const float*)d_in[4];
  const float* b_hh0 = (const float*)d_in[5];
  const float* W_ih1 = (const float*)d_in[6];
  const float* W_hh1 = (const float*)d_in[7];
  const float* b_ih1 = (const float*)d_in[8];
  const float* b_hh1 = (const float*)d_in[9];
  const float* W_out = (const float*)d_in[10];
  const float* b_out = (const float*)d_in[11];
  float* Y = (float*)d_out;

  // ws carve: bar first (256 KB, 16B-aligned end), then bf16 data (~5.1 MiB)
  u32* bar  = (u32*)d_ws;             // BAR_U32 u32 (events + done line)
  u16* WL0  = (u16*)(bar + BAR_U32);  // 1536*768
  u16* WL1  = WL0 + 1536 * 768;       // 2048*512
  u16* WOB  = WL1 + 2048 * 512;       // 256*512
  u16* HbB0 = WOB + 256 * 512;        // 128*512
  u16* HbB1 = HbB0 + 128 * 512;
  u16* hLB  = HbB1 + 128 * 512;

  prep_kernel<<<dim3(1024), dim3(256), 0, stream>>>(W_ih0, W_hh0, W_ih1, W_hh1,
                                                    W_out, h0, WL0, WL1, WOB,
                                                    HbB0, bar);
  gru_persist<<<dim3(NALL), dim3(256), 0, stream>>>(
      x, h0, b_ih0, b_hh0, b_ih1, b_hh1, b_out, WL0, WL1, WOB,
      HbB0, HbB1, hLB, Y, bar);
}

// Round 12
// 12605.279 us; speedup vs baseline: 1.2373x; 1.1591x over previous
//
#include <hip/hip_runtime.h>

// B=128, T=512, I=256, H=512, O=256. GRU (r,z,n), 2 layers sharing one hidden
// state (quirk), y_t = h @ W_out^T + b_out.
//
// Round 12: round-11 structure (64 real + 160 heater blocks, MALL sc0|sc1
// data path, register carries, y fused on hb registers) with a DECONGESTED
// barrier (theory: 30us/step was poller-induced MALL line congestion):
//  - arrival: each block stores monotonic t+1 to its OWN 128B line (64 lines)
//  - only block 0 wave 0 polls: 64-lane gather of all flags, 1 reader/line
//  - grant: 8 go-lines (t+1, monotonic); members poll their line: <=8 pollers
//    per line with ~0.27us backoff. Zero RMWs. Deadlock-free (monotonic).

typedef short s16x8 __attribute__((ext_vector_type(8)));  // 8 bf16
typedef float f32x4 __attribute__((ext_vector_type(4)));
typedef unsigned short u16;
typedef unsigned int u32;

#define MFMA(a, b, c) __builtin_amdgcn_mfma_f32_16x16x32_bf16((a), (b), (c), 0, 0, 0)

static constexpr int NREAL = 64;
static constexpr int NHEAT = 160;
static constexpr int NALL  = 224;
static constexpr int HEAT_CAP = 30000;
// bar layout (u32 idx): FLA[64*32] | FLB[64*32] | GOA[8*32] | GOB[8*32] | DONE
static constexpr int FLA = 0, FLB = 2048, GOA = 4096, GOB = 4352, DONE = 4608;
static constexpr int BAR_U32 = 4624;

__device__ __forceinline__ u16 f2bf(float f) {
  unsigned u = __builtin_bit_cast(unsigned, f);
  u = u + 0x7fffu + ((u >> 16) & 1u);
  return (u16)(u >> 16);
}
__device__ __forceinline__ float sigm(float x) { return 1.f / (1.f + __expf(-x)); }
__device__ __forceinline__ float tanh_f(float x) { return 1.f - 2.f / (1.f + __expf(2.f * x)); }

// ---- MALL-direct helpers (rounds 5/9/11 proven) ----
__device__ __forceinline__ s16x8 scload16(const u16* p) {
  s16x8 v;
  asm volatile("global_load_dwordx4 %0, %1, off sc0 sc1" : "=v"(v) : "v"(p));
  return v;  // valid only after VWAIT0()
}
__device__ __forceinline__ void scstore_u16(u16* p, u16 v) {
  unsigned vv = v;
  asm volatile("global_store_short %0, %1, off sc0 sc1" :: "v"(p), "v"(vv) : "memory");
}
#define VWAIT0()                                        \
  do {                                                  \
    asm volatile("s_waitcnt vmcnt(0)" ::: "memory");    \
    __builtin_amdgcn_sched_barrier(0);                  \
  } while (0)

// Decongested grid barrier: flags = 64 lines (one per block), go = 8 lines.
// All values monotonic (t+1); no resets, no RMWs.
__device__ __forceinline__ void fbar(u32* flags, u32* go, u32 val, int blk) {
  asm volatile("s_waitcnt vmcnt(0)" ::: "memory");  // data stores acked @ MALL
  __syncthreads();
  if (blk == 0) {
    if (threadIdx.x == 0) {
      asm volatile("global_store_dword %0, %1, off sc0 sc1"
                   :: "v"(flags), "v"(val) : "memory");
    }
    if (threadIdx.x < 64) {                 // wave 0: 64-lane gather poll
      const u32* p = flags + threadIdx.x * 32;
      u32 v;
      for (;;) {
        asm volatile("global_load_dword %0, %1, off sc0 sc1\n\ts_waitcnt vmcnt(0)"
                     : "=v"(v) : "v"(p) : "memory");
        if (__all(v >= val)) break;
        __builtin_amdgcn_s_sleep(4);
      }
      if (threadIdx.x < 8) {                // grant on 8 go-lines
        asm volatile("global_store_dword %0, %1, off sc0 sc1"
                     :: "v"(go + threadIdx.x * 32), "v"(val) : "memory");
      }
    }
  } else {
    if (threadIdx.x == 0) {
      asm volatile("global_store_dword %0, %1, off sc0 sc1"
                   :: "v"(flags + blk * 32), "v"(val) : "memory");
      const u32* p = go + (blk & 7) * 32;
      u32 v;
      do {
        __builtin_amdgcn_s_sleep(10);
        asm volatile("global_load_dword %0, %1, off sc0 sc1\n\ts_waitcnt vmcnt(0)"
                     : "=v"(v) : "v"(p) : "memory");
      } while (v < val);
    }
  }
  __syncthreads();
}

// ---------------- weight prep + barrier reset (once per call) ----------------
__global__ void prep_kernel(const float* __restrict__ W_ih0, const float* __restrict__ W_hh0,
                            const float* __restrict__ W_ih1, const float* __restrict__ W_hh1,
                            const float* __restrict__ W_out, const float* __restrict__ h0,
                            u16* __restrict__ WL0, u16* __restrict__ WL1,
                            u16* __restrict__ WOB, u16* __restrict__ HbB0,
                            u32* __restrict__ bar) {
  const int n0 = 1536 * 768, n1 = 2048 * 512, n2 = 256 * 512, n3 = 128 * 512;
  const int total = n0 + n1 + n2 + n3 + BAR_U32;
  for (int i = blockIdx.x * blockDim.x + threadIdx.x; i < total; i += gridDim.x * blockDim.x) {
    if (i < n0) {
      int row = i / 768, c = i % 768;
      float v = (c < 256) ? W_ih0[row * 256 + c] : W_hh0[row * 512 + (c - 256)];
      WL0[i] = f2bf(v);
    } else if (i < n0 + n1) {
      int k2 = i - n0;
      int row = k2 / 512, k = k2 % 512;
      int strip = row >> 9, j = row & 511;
      float v;
      if (strip == 0)      v = W_ih1[j * 512 + k] + W_hh1[j * 512 + k];
      else if (strip == 1) v = W_ih1[(512 + j) * 512 + k] + W_hh1[(512 + j) * 512 + k];
      else if (strip == 2) v = W_ih1[(1024 + j) * 512 + k];
      else                 v = W_hh1[(1024 + j) * 512 + k];
      WL1[k2] = f2bf(v);
    } else if (i < n0 + n1 + n2) {
      int k2 = i - n0 - n1;
      WOB[k2] = f2bf(W_out[k2]);
    } else if (i < n0 + n1 + n2 + n3) {
      int k2 = i - n0 - n1 - n2;
      HbB0[k2] = f2bf(h0[k2]);
    } else {
      bar[i - n0 - n1 - n2 - n3] = 0u;
    }
  }
}

// ---------------- persistent GRU kernel (64 real + 160 heater blocks) --------
__global__ __launch_bounds__(256) void gru_persist(
    const float* __restrict__ x, const float* __restrict__ h0,
    const float* __restrict__ b_ih0, const float* __restrict__ b_hh0,
    const float* __restrict__ b_ih1, const float* __restrict__ b_hh1,
    const float* __restrict__ b_out,
    const u16* __restrict__ WL0, const u16* __restrict__ WL1, const u16* __restrict__ WOB,
    u16* __restrict__ HbB0, u16* __restrict__ HbB1, u16* __restrict__ hLB,
    float* __restrict__ Y, u32* __restrict__ bar) {
  const int blk = blockIdx.x;
  u32* done = bar + DONE;

  if (blk >= NREAL) {
    // ---- heater: keeps DPM clocks boosted; polls done every ~14us ----
    float a0 = 1.0f + threadIdx.x * 1e-6f, a1 = 1.1f, a2 = 1.2f, a3 = 1.3f;
    float a4 = 1.4f, a5 = 1.5f, a6 = 1.6f, a7 = 1.7f;
    for (int it = 0; it < HEAT_CAP; ++it) {
      #pragma unroll 32
      for (int k = 0; k < 2048; ++k) {
        a0 = __builtin_fmaf(a0, 0.9999999f, 1e-9f);
        a1 = __builtin_fmaf(a1, 0.9999999f, 1e-9f);
        a2 = __builtin_fmaf(a2, 0.9999999f, 1e-9f);
        a3 = __builtin_fmaf(a3, 0.9999999f, 1e-9f);
        a4 = __builtin_fmaf(a4, 0.9999999f, 1e-9f);
        a5 = __builtin_fmaf(a5, 0.9999999f, 1e-9f);
        a6 = __builtin_fmaf(a6, 0.9999999f, 1e-9f);
        a7 = __builtin_fmaf(a7, 0.9999999f, 1e-9f);
      }
      u32 d;
      asm volatile("global_load_dword %0, %1, off sc0 sc1\n\ts_waitcnt vmcnt(0)"
                   : "=v"(d) : "v"((const u32*)done) : "memory");
      if (d) break;
    }
    asm volatile("" :: "v"(a0), "v"(a1), "v"(a2), "v"(a3),
                       "v"(a4), "v"(a5), "v"(a6), "v"(a7));
    return;
  }

  const int w = threadIdx.x >> 6, l = threadIdx.x & 63;
  const int l15 = l & 15, l4 = l >> 4;

  // ---- task mapping (round-5/11 proven) ----
  const int cg = blk & 31;
  const int mt = (blk >> 5) * 4 + w;
  const int brow = mt * 16 + l15;
  const int jg = cg * 16 + l15;
  const int b0 = mt * 16 + l4 * 4;
  const u16* wr  = WL0 + (size_t)jg * 768 + l4 * 8;
  const u16* wz  = WL0 + (size_t)(512 + jg) * 768 + l4 * 8;
  const u16* wn  = WL0 + (size_t)(1024 + jg) * 768 + l4 * 8;
  const u16* w10 = WL1 + (size_t)jg * 512 + l4 * 8;
  const u16* w11 = w10 + 512 * 512;
  const u16* w12 = w10 + 1024 * 512;
  const u16* w13 = w10 + 1536 * 512;
  const float br0 = b_ih0[jg] + b_hh0[jg];
  const float bz0 = b_ih0[512 + jg] + b_hh0[512 + jg];
  const float bni0 = b_ih0[1024 + jg], bnh0 = b_hh0[1024 + jg];
  const float br1 = b_ih1[jg] + b_hh1[jg];
  const float bz1 = b_ih1[512 + jg] + b_hh1[512 + jg];
  const float bni1 = b_ih1[1024 + jg], bnh1 = b_hh1[1024 + jg];
  const float* xrow = x + (size_t)brow * 512 * 256 + l4 * 8;

  float hreg[4], hl[4];
  #pragma unroll
  for (int j = 0; j < 4; ++j) hreg[j] = h0[(size_t)(b0 + j) * 512 + jg];

  // ---- fused y mapping (round-11 proven): even-cg waves ----
  const bool ywave = ((cg & 1) == 0);
  const int yo = (cg >> 1) * 16 + l15;
  const float ybo = b_out[yo];
  const u16* ywv = WOB + (size_t)yo * 512 + l4 * 8;

  u32* flA = bar + FLA; u32* goA = bar + GOA;
  u32* flB = bar + FLB; u32* goB = bar + GOB;

  for (int t = 0; t < 512; ++t) {
    u16* HbBc = (t & 1) ? HbB1 : HbB0;     // h(t-1)
    u16* HbBn = (t & 1) ? HbB0 : HbB1;     // h(t) dest

    // ---- phase A, x-part FIRST (no cross-block deps; hides B-grant) ----
    f32x4 aR = {0,0,0,0}, aZ = {0,0,0,0}, aNI = {0,0,0,0}, aNH = {0,0,0,0};
    const float* xr = xrow + (size_t)t * 256;
    #pragma unroll
    for (int kt = 0; kt < 8; ++kt) {
      float4 u = *(const float4*)(xr + kt * 32);
      float4 v = *(const float4*)(xr + kt * 32 + 4);
      s16x8 a;
      a[0] = f2bf(u.x); a[1] = f2bf(u.y); a[2] = f2bf(u.z); a[3] = f2bf(u.w);
      a[4] = f2bf(v.x); a[5] = f2bf(v.y); a[6] = f2bf(v.z); a[7] = f2bf(v.w);
      aR  = MFMA(a, *(const s16x8*)(wr + kt * 32), aR);
      aZ  = MFMA(a, *(const s16x8*)(wz + kt * 32), aZ);
      aNI = MFMA(a, *(const s16x8*)(wn + kt * 32), aNI);
    }

    // h(t-1) buffer is safe only after B(t-1) globally done (t=0: prep did it)
    if (t > 0) {
      // already arrived at B(t-1) barrier inside previous iteration; nothing
    }

    // ---- h-part: load h(t-1), MFMA; hb also feeds fused y ----
    s16x8 hb[16];
    {
      const u16* hr = HbBc + (size_t)brow * 512 + l4 * 8;
      #pragma unroll
      for (int kt = 0; kt < 16; ++kt) hb[kt] = scload16(hr + kt * 32);
    }
    VWAIT0();
    #pragma unroll
    for (int kt = 0; kt < 16; ++kt) {
      aR  = MFMA(hb[kt], *(const s16x8*)(wr + (8 + kt) * 32), aR);
      aZ  = MFMA(hb[kt], *(const s16x8*)(wz + (8 + kt) * 32), aZ);
      aNH = MFMA(hb[kt], *(const s16x8*)(wn + (8 + kt) * 32), aNH);
    }

    // ---- fused y(t-1) from hb registers ----
    if (ywave && t > 0) {
      f32x4 acc = {0,0,0,0};
      #pragma unroll
      for (int kt = 0; kt < 16; ++kt)
        acc = MFMA(hb[kt], *(const s16x8*)(ywv + kt * 32), acc);
      #pragma unroll
      for (int j = 0; j < 4; ++j)
        Y[((size_t)(b0 + j) * 512 + (t - 1)) * 256 + yo] = acc[j] + ybo;
    }

    // ---- L0 epilogue -> hl stores ----
    #pragma unroll
    for (int j = 0; j < 4; ++j) {
      float r = sigm(aR[j] + br0);
      float z = sigm(aZ[j] + bz0);
      float n = tanh_f(aNI[j] + bni0 + r * (aNH[j] + bnh0));
      float h = (1.f - z) * n + z * hreg[j];
      hl[j] = h;
      scstore_u16(&hLB[(size_t)(b0 + j) * 512 + jg], f2bf(h));
    }
    fbar(flA, goA, (u32)(t + 1), blk);

    // ---- phase B: layer 1 (input == hidden == h_l0) ----
    f32x4 cR = {0,0,0,0}, cZ = {0,0,0,0}, cNI = {0,0,0,0}, cNH = {0,0,0,0};
    {
      s16x8 pb[16];
      const u16* ar = hLB + (size_t)brow * 512 + l4 * 8;
      #pragma unroll
      for (int kt = 0; kt < 16; ++kt) pb[kt] = scload16(ar + kt * 32);
      VWAIT0();
      #pragma unroll
      for (int kt = 0; kt < 16; ++kt) {
        cR  = MFMA(pb[kt], *(const s16x8*)(w10 + kt * 32), cR);
        cZ  = MFMA(pb[kt], *(const s16x8*)(w11 + kt * 32), cZ);
        cNI = MFMA(pb[kt], *(const s16x8*)(w12 + kt * 32), cNI);
        cNH = MFMA(pb[kt], *(const s16x8*)(w13 + kt * 32), cNH);
      }
    }
    #pragma unroll
    for (int j = 0; j < 4; ++j) {
      float r = sigm(cR[j] + br1);
      float z = sigm(cZ[j] + bz1);
      float n = tanh_f(cNI[j] + bni1 + r * (cNH[j] + bnh1));
      float h = (1.f - z) * n + z * hl[j];
      hreg[j] = h;
      scstore_u16(&HbBn[(size_t)(b0 + j) * 512 + jg], f2bf(h));
    }
    fbar(flB, goB, (u32)(t + 1), blk);
  }

  // ---- stop heaters ----
  if (blk == 0 && threadIdx.x == 0) {
    unsigned one = 1u;
    asm volatile("global_store_dword %0, %1, off sc0 sc1" :: "v"(done), "v"(one) : "memory");
  }

  // ---- final y (t = 511): h(511) is in buffer 0 ----
  if (ywave) {
    s16x8 yb[16];
    const u16* ar = HbB0 + (size_t)brow * 512 + l4 * 8;
    #pragma unroll
    for (int kt = 0; kt < 16; ++kt) yb[kt] = scload16(ar + kt * 32);
    VWAIT0();
    f32x4 acc = {0,0,0,0};
    #pragma unroll
    for (int kt = 0; kt < 16; ++kt)
      acc = MFMA(yb[kt], *(const s16x8*)(ywv + kt * 32), acc);
    #pragma unroll
    for (int j = 0; j < 4; ++j)
      Y[((size_t)(b0 + j) * 512 + 511) * 256 + yo] = acc[j] + ybo;
  }
}

extern "C" void kernel_launch(void* const* d_in, const int* in_sizes, int n_in,
                              void* d_out, int out_size, void* d_ws, size_t ws_size,
                              hipStream_t stream) {
  const float* x     = (const float*)d_in[0];
  const float* h0    = (const float*)d_in[1];
  const float* W_ih0 = (const float*)d_in[2];
  const float* W_hh0 = (const float*)d_in[3];
  const float* b_ih0 = (const float*)d_in[4];
  const float* b_hh0 = (const float*)d_in[5];
  const float* W_ih1 = (const float*)d_in[6];
  const float* W_hh1 = (const float*)d_in[7];
  const float* b_ih1 = (const float*)d_in[8];
  const float* b_hh1 = (const float*)d_in[9];
  const float* W_out = (const float*)d_in[10];
  const float* b_out = (const float*)d_in[11];
  float* Y = (float*)d_out;

  // ws carve: bar first (18.5 KB), then bf16 data (~5.1 MiB)
  u32* bar  = (u32*)d_ws;
  u16* WL0  = (u16*)(bar + BAR_U32);
  u16* WL1  = WL0 + 1536 * 768;
  u16* WOB  = WL1 + 2048 * 512;
  u16* HbB0 = WOB + 256 * 512;
  u16* HbB1 = HbB0 + 128 * 512;
  u16* hLB  = HbB1 + 128 * 512;

  prep_kernel<<<dim3(1024), dim3(256), 0, stream>>>(W_ih0, W_hh0, W_ih1, W_hh1,
                                                    W_out, h0, WL0, WL1, WOB,
                                                    HbB0, bar);
  gru_persist<<<dim3(NALL), dim3(256), 0, stream>>>(
      x, h0, b_ih0, b_hh0, b_ih1, b_hh1, b_out, WL0, WL1, WOB,
      HbB0, HbB1, hLB, Y, bar);
}

// Round 13
// 8525.328 us; speedup vs baseline: 1.8295x; 1.4786x over previous
//
#include <hip/hip_runtime.h>

// B=128, T=512, I=256, H=512, O=256. GRU (r,z,n), 2 layers sharing one hidden
// state (quirk), y_t = h @ W_out^T + b_out.
//
// Round 13: batch rows are INDEPENDENT -> 4 machines x 32 rows, each machine
// = 32 blocks (16 hidden cols each). Per block: W_hh0/W_hh1 slice (116 KB)
// lives in LDS (loaded once -> zero weight traffic in loop). Wave roles:
// w0 = L0 (x-part from global overlaps h-load RT), w1 = L1, w2 = y(t-1).
// f32 carries in LDS (wave0 <-> wave1, ordered by barrier syncthreads).
// Per-machine barrier: monotonic sc-flag all-gather (rounds 9/12 proven
// primitives; no RMW, no narrow scopes). 128 blocks x 256 thr, 1 block/CU.

typedef short s16x8 __attribute__((ext_vector_type(8)));  // 8 bf16
typedef float f32x4 __attribute__((ext_vector_type(4)));
typedef unsigned short u16;
typedef unsigned int u32;

#define MFMA(a, b, c) __builtin_amdgcn_mfma_f32_16x16x32_bf16((a), (b), (c), 0, 0, 0)

static constexpr int NBLK = 128;       // 4 machines x 32 slices
static constexpr int LDS_WROWS = 112;  // 48 L0h + 64 L1 rows
static constexpr int LDS_STRIDE = 520; // 512 elems + 8 pad (1040 B, bank-shift 4)
static constexpr int LDS_BYTES = LDS_WROWS * LDS_STRIDE * 2 + 2 * 512 * 4;
static constexpr int FLAGS_U32 = 8192; // 2 arrays x 4 machines x 32 lines x 32

__device__ __forceinline__ u16 f2bf(float f) {
  unsigned u = __builtin_bit_cast(unsigned, f);
  u = u + 0x7fffu + ((u >> 16) & 1u);
  return (u16)(u >> 16);
}
__device__ __forceinline__ float sigm(float x) { return 1.f / (1.f + __expf(-x)); }
__device__ __forceinline__ float tanh_f(float x) { return 1.f - 2.f / (1.f + __expf(2.f * x)); }

// ---- MALL-direct helpers (rounds 5/9/11/12 proven) ----
__device__ __forceinline__ s16x8 scload16(const u16* p) {
  s16x8 v;
  asm volatile("global_load_dwordx4 %0, %1, off sc0 sc1" : "=v"(v) : "v"(p));
  return v;  // valid only after VWAIT0()
}
__device__ __forceinline__ void scstore_u16(u16* p, u16 v) {
  unsigned vv = v;
  asm volatile("global_store_short %0, %1, off sc0 sc1" :: "v"(p), "v"(vv) : "memory");
}
#define VWAIT0()                                        \
  do {                                                  \
    asm volatile("s_waitcnt vmcnt(0)" ::: "memory");    \
    __builtin_amdgcn_sched_barrier(0);                  \
  } while (0)

// Per-machine barrier: 32 monotonic flag lines; every block self-gathers with
// wave 0's lanes 0..31. No grant hop, no RMW. Deadlock-free (monotonic vals,
// all 128 blocks resident at 1 block/CU).
__device__ __forceinline__ void fbar(u32* fbase, int s, u32 val) {
  asm volatile("s_waitcnt vmcnt(0)" ::: "memory");  // drain data sc-stores
  __syncthreads();
  if (threadIdx.x == 0) {
    asm volatile("global_store_dword %0, %1, off sc0 sc1"
                 :: "v"(fbase + s * 32), "v"(val) : "memory");
  }
  if (threadIdx.x < 64) {
    const int lane = threadIdx.x;
    const u32* p = fbase + lane * 32;
    for (;;) {
      int ok = 1;
      if (lane < 32) {
        u32 v;
        asm volatile("global_load_dword %0, %1, off sc0 sc1\n\ts_waitcnt vmcnt(0)"
                     : "=v"(v) : "v"(p) : "memory");
        ok = (v >= val) ? 1 : 0;
      }
      if (__all(ok)) break;
      __builtin_amdgcn_s_sleep(1);
    }
  }
  __syncthreads();
}

// ---------------- weight prep + init (once per call) ----------------
__global__ void prep_kernel(const float* __restrict__ W_ih0, const float* __restrict__ W_hh0,
                            const float* __restrict__ W_ih1, const float* __restrict__ W_hh1,
                            const float* __restrict__ W_out, const float* __restrict__ h0,
                            u16* __restrict__ WL0, u16* __restrict__ WL1,
                            u16* __restrict__ WOB, u16* __restrict__ ring1,
                            u32* __restrict__ flags) {
  const int n0 = 1536 * 768, n1 = 2048 * 512, n2 = 256 * 512, n3 = 128 * 512;
  const int total = n0 + n1 + n2 + n3 + FLAGS_U32;
  for (int i = blockIdx.x * blockDim.x + threadIdx.x; i < total; i += gridDim.x * blockDim.x) {
    if (i < n0) {
      int row = i / 768, c = i % 768;
      float v = (c < 256) ? W_ih0[row * 256 + c] : W_hh0[row * 512 + (c - 256)];
      WL0[i] = f2bf(v);
    } else if (i < n0 + n1) {
      int k2 = i - n0;
      int row = k2 / 512, k = k2 % 512;
      int strip = row >> 9, j = row & 511;
      float v;
      if (strip == 0)      v = W_ih1[j * 512 + k] + W_hh1[j * 512 + k];
      else if (strip == 1) v = W_ih1[(512 + j) * 512 + k] + W_hh1[(512 + j) * 512 + k];
      else if (strip == 2) v = W_ih1[(1024 + j) * 512 + k];
      else                 v = W_hh1[(1024 + j) * 512 + k];
      WL1[k2] = f2bf(v);
    } else if (i < n0 + n1 + n2) {
      int k2 = i - n0 - n1;
      WOB[k2] = f2bf(W_out[k2]);
    } else if (i < n0 + n1 + n2 + n3) {
      int k2 = i - n0 - n1 - n2;
      ring1[k2] = f2bf(h0[k2]);     // ring[1] = h(-1) = h0
    } else {
      flags[i - n0 - n1 - n2 - n3] = 0u;
    }
  }
}

// ---------------- persistent GRU kernel (128 blocks x 256 thr) ---------------
__global__ __launch_bounds__(256) void gru_persist(
    const float* __restrict__ x, const float* __restrict__ h0,
    const float* __restrict__ b_ih0, const float* __restrict__ b_hh0,
    const float* __restrict__ b_ih1, const float* __restrict__ b_hh1,
    const float* __restrict__ b_out,
    const u16* __restrict__ WL0, const u16* __restrict__ WL1, const u16* __restrict__ WOB,
    u16* __restrict__ ring,      // [2][128][512] bf16
    u16* __restrict__ hlb,       // [128][512] bf16
    float* __restrict__ Y, u32* __restrict__ flagsA, u32* __restrict__ flagsB) {
  extern __shared__ u16 smem[];
  float* h_f32  = (float*)(smem + LDS_WROWS * LDS_STRIDE);  // [32][16]
  float* hl_f32 = h_f32 + 512;                              // [32][16]

  const int blk = blockIdx.x;
  const int m = blk >> 5;       // machine 0..3 (rows 32m..32m+31)
  const int s = blk & 31;       // hidden-col slice (cols s*16..s*16+15)
  const int w = threadIdx.x >> 6, l = threadIdx.x & 63;
  const int l15 = l & 15, l4 = l >> 4;

  // ---- init: weight slice -> LDS ----
  for (int idx = threadIdx.x; idx < LDS_WROWS * 512; idx += 256) {
    int row = idx >> 9, k = idx & 511;
    u16 v;
    if (row < 48) {             // L0 h-part: gates r,z,n; K = 512 (offset 256)
      int g = row >> 4, jj = row & 15;
      v = WL0[(size_t)(g * 512 + s * 16 + jj) * 768 + 256 + k];
    } else {                    // L1: gates r,z,ni,nh; K = 512
      int rr = row - 48, g = rr >> 4, jj = rr & 15;
      v = WL1[(size_t)(g * 512 + s * 16 + jj) * 512 + k];
    }
    smem[row * LDS_STRIDE + k] = v;
  }
  for (int idx = threadIdx.x; idx < 512; idx += 256) {  // f32 carry init
    int rr = idx >> 4, cc = idx & 15;
    h_f32[idx] = h0[(size_t)(32 * m + rr) * 512 + s * 16 + cc];
  }
  __syncthreads();

  const int jg = s * 16 + l15;
  const float br0 = b_ih0[jg] + b_hh0[jg];
  const float bz0 = b_ih0[512 + jg] + b_hh0[512 + jg];
  const float bni0 = b_ih0[1024 + jg], bnh0 = b_hh0[1024 + jg];
  const float br1 = b_ih1[jg] + b_hh1[jg];
  const float bz1 = b_ih1[512 + jg] + b_hh1[512 + jg];
  const float bni1 = b_ih1[1024 + jg], bnh1 = b_hh1[1024 + jg];

  // wave0: x-part weights (global, L2-hot; streamed during waits)
  const u16* wxr = WL0 + (size_t)jg * 768 + l4 * 8;
  const u16* wxz = WL0 + (size_t)(512 + jg) * 768 + l4 * 8;
  const u16* wxn = WL0 + (size_t)(1024 + jg) * 768 + l4 * 8;
  // LDS B-frag bases
  const u16* lr  = smem + (0 * 16 + l15) * LDS_STRIDE + l4 * 8;
  const u16* lz  = smem + (1 * 16 + l15) * LDS_STRIDE + l4 * 8;
  const u16* ln  = smem + (2 * 16 + l15) * LDS_STRIDE + l4 * 8;
  const u16* m10 = smem + (48 + 0 * 16 + l15) * LDS_STRIDE + l4 * 8;
  const u16* m11 = smem + (48 + 1 * 16 + l15) * LDS_STRIDE + l4 * 8;
  const u16* m12 = smem + (48 + 2 * 16 + l15) * LDS_STRIDE + l4 * 8;
  const u16* m13 = smem + (48 + 3 * 16 + l15) * LDS_STRIDE + l4 * 8;

  // wave2: y tile — col-group s&15, M-tile s>>4
  const int yMt = s >> 4, ycg = s & 15;
  const int yo = ycg * 16 + l15;
  const float ybo = b_out[yo];
  const u16* ywv = WOB + (size_t)yo * 512 + l4 * 8;
  const int yrow = 32 * m + yMt * 16;

  u32* fA = flagsA + m * 1024;   // machine's 32 flag lines (A)
  u32* fB = flagsB + m * 1024;   // (B)

  for (int t = 0; t < 512; ++t) {
    const u16* ringc = ring + (size_t)((t + 1) & 1) * 65536;  // h(t-1)
    u16* ringn = ring + (size_t)(t & 1) * 65536;              // h(t) dest

    if (w == 0) {
      // ---- phase A: L0 for cols jg, M-tiles 0,1 ----
      s16x8 hb0[16], hb1[16];
      const u16* hr0 = ringc + (size_t)(32 * m + l15) * 512 + l4 * 8;
      const u16* hr1 = ringc + (size_t)(32 * m + 16 + l15) * 512 + l4 * 8;
      #pragma unroll
      for (int kt = 0; kt < 16; ++kt) hb0[kt] = scload16(hr0 + kt * 32);
      #pragma unroll
      for (int kt = 0; kt < 16; ++kt) hb1[kt] = scload16(hr1 + kt * 32);

      f32x4 aR0 = {0,0,0,0}, aZ0 = {0,0,0,0}, aNI0 = {0,0,0,0}, aNH0 = {0,0,0,0};
      f32x4 aR1 = {0,0,0,0}, aZ1 = {0,0,0,0}, aNI1 = {0,0,0,0}, aNH1 = {0,0,0,0};
      const float* xr0 = x + ((size_t)(32 * m + l15) * 512 + t) * 256 + l4 * 8;
      const float* xr1 = x + ((size_t)(32 * m + 16 + l15) * 512 + t) * 256 + l4 * 8;
      #pragma unroll
      for (int kt = 0; kt < 8; ++kt) {
        float4 u0 = *(const float4*)(xr0 + kt * 32);
        float4 v0 = *(const float4*)(xr0 + kt * 32 + 4);
        float4 u1 = *(const float4*)(xr1 + kt * 32);
        float4 v1 = *(const float4*)(xr1 + kt * 32 + 4);
        s16x8 a0, a1;
        a0[0]=f2bf(u0.x); a0[1]=f2bf(u0.y); a0[2]=f2bf(u0.z); a0[3]=f2bf(u0.w);
        a0[4]=f2bf(v0.x); a0[5]=f2bf(v0.y); a0[6]=f2bf(v0.z); a0[7]=f2bf(v0.w);
        a1[0]=f2bf(u1.x); a1[1]=f2bf(u1.y); a1[2]=f2bf(u1.z); a1[3]=f2bf(u1.w);
        a1[4]=f2bf(v1.x); a1[5]=f2bf(v1.y); a1[6]=f2bf(v1.z); a1[7]=f2bf(v1.w);
        s16x8 br = *(const s16x8*)(wxr + kt * 32);
        s16x8 bz = *(const s16x8*)(wxz + kt * 32);
        s16x8 bn = *(const s16x8*)(wxn + kt * 32);
        aR0 = MFMA(a0, br, aR0);  aR1 = MFMA(a1, br, aR1);
        aZ0 = MFMA(a0, bz, aZ0);  aZ1 = MFMA(a1, bz, aZ1);
        aNI0 = MFMA(a0, bn, aNI0); aNI1 = MFMA(a1, bn, aNI1);
      }
      VWAIT0();
      #pragma unroll
      for (int kt = 0; kt < 16; ++kt) {
        s16x8 br = *(const s16x8*)(lr + kt * 32);
        s16x8 bz = *(const s16x8*)(lz + kt * 32);
        s16x8 bn = *(const s16x8*)(ln + kt * 32);
        aR0 = MFMA(hb0[kt], br, aR0);  aR1 = MFMA(hb1[kt], br, aR1);
        aZ0 = MFMA(hb0[kt], bz, aZ0);  aZ1 = MFMA(hb1[kt], bz, aZ1);
        aNH0 = MFMA(hb0[kt], bn, aNH0); aNH1 = MFMA(hb1[kt], bn, aNH1);
      }
      #pragma unroll
      for (int j = 0; j < 4; ++j) {
        {
          int rr = l4 * 4 + j;
          float r = sigm(aR0[j] + br0), z = sigm(aZ0[j] + bz0);
          float n = tanh_f(aNI0[j] + bni0 + r * (aNH0[j] + bnh0));
          float h = (1.f - z) * n + z * h_f32[rr * 16 + l15];
          hl_f32[rr * 16 + l15] = h;
          scstore_u16(hlb + (size_t)(32 * m + rr) * 512 + jg, f2bf(h));
        }
        {
          int rr = 16 + l4 * 4 + j;
          float r = sigm(aR1[j] + br0), z = sigm(aZ1[j] + bz0);
          float n = tanh_f(aNI1[j] + bni0 + r * (aNH1[j] + bnh0));
          float h = (1.f - z) * n + z * h_f32[rr * 16 + l15];
          hl_f32[rr * 16 + l15] = h;
          scstore_u16(hlb + (size_t)(32 * m + rr) * 512 + jg, f2bf(h));
        }
      }
    } else if (w == 2 && t > 0) {
      // ---- y(t-1), concurrent with phase A ----
      s16x8 yb[16];
      const u16* ar = ringc + (size_t)(yrow + l15) * 512 + l4 * 8;
      #pragma unroll
      for (int kt = 0; kt < 16; ++kt) yb[kt] = scload16(ar + kt * 32);
      VWAIT0();
      f32x4 acc = {0,0,0,0};
      #pragma unroll
      for (int kt = 0; kt < 16; ++kt)
        acc = MFMA(yb[kt], *(const s16x8*)(ywv + kt * 32), acc);
      #pragma unroll
      for (int j = 0; j < 4; ++j)
        Y[((size_t)(yrow + l4 * 4 + j) * 512 + (t - 1)) * 256 + yo] = acc[j] + ybo;
    }
    fbar(fA, s, (u32)(t + 1));

    if (w == 1) {
      // ---- phase B: L1 (input == hidden == h_l0) ----
      s16x8 pb0[16], pb1[16];
      const u16* ar0 = hlb + (size_t)(32 * m + l15) * 512 + l4 * 8;
      const u16* ar1 = hlb + (size_t)(32 * m + 16 + l15) * 512 + l4 * 8;
      #pragma unroll
      for (int kt = 0; kt < 16; ++kt) pb0[kt] = scload16(ar0 + kt * 32);
      #pragma unroll
      for (int kt = 0; kt < 16; ++kt) pb1[kt] = scload16(ar1 + kt * 32);
      VWAIT0();
      f32x4 cR0 = {0,0,0,0}, cZ0 = {0,0,0,0}, cNI0 = {0,0,0,0}, cNH0 = {0,0,0,0};
      f32x4 cR1 = {0,0,0,0}, cZ1 = {0,0,0,0}, cNI1 = {0,0,0,0}, cNH1 = {0,0,0,0};
      #pragma unroll
      for (int kt = 0; kt < 16; ++kt) {
        s16x8 b0 = *(const s16x8*)(m10 + kt * 32);
        s16x8 b1 = *(const s16x8*)(m11 + kt * 32);
        s16x8 b2 = *(const s16x8*)(m12 + kt * 32);
        s16x8 b3 = *(const s16x8*)(m13 + kt * 32);
        cR0 = MFMA(pb0[kt], b0, cR0);  cR1 = MFMA(pb1[kt], b0, cR1);
        cZ0 = MFMA(pb0[kt], b1, cZ0);  cZ1 = MFMA(pb1[kt], b1, cZ1);
        cNI0 = MFMA(pb0[kt], b2, cNI0); cNI1 = MFMA(pb1[kt], b2, cNI1);
        cNH0 = MFMA(pb0[kt], b3, cNH0); cNH1 = MFMA(pb1[kt], b3, cNH1);
      }
      #pragma unroll
      for (int j = 0; j < 4; ++j) {
        {
          int rr = l4 * 4 + j;
          float r = sigm(cR0[j] + br1), z = sigm(cZ0[j] + bz1);
          float n = tanh_f(cNI0[j] + bni1 + r * (cNH0[j] + bnh1));
          float h = (1.f - z) * n + z * hl_f32[rr * 16 + l15];
          h_f32[rr * 16 + l15] = h;
          scstore_u16(ringn + (size_t)(32 * m + rr) * 512 + jg, f2bf(h));
        }
        {
          int rr = 16 + l4 * 4 + j;
          float r = sigm(cR1[j] + br1), z = sigm(cZ1[j] + bz1);
          float n = tanh_f(cNI1[j] + bni1 + r * (cNH1[j] + bnh1));
          float h = (1.f - z) * n + z * hl_f32[rr * 16 + l15];
          h_f32[rr * 16 + l15] = h;
          scstore_u16(ringn + (size_t)(32 * m + rr) * 512 + jg, f2bf(h));
        }
      }
    }
    fbar(fB, s, (u32)(t + 1));
  }

  // ---- final y (t = 511): h(511) is in ring[1] ----
  if (w == 2) {
    const u16* Hf = ring + 65536;
    s16x8 yb[16];
    const u16* ar = Hf + (size_t)(yrow + l15) * 512 + l4 * 8;
    #pragma unroll
    for (int kt = 0; kt < 16; ++kt) yb[kt] = scload16(ar + kt * 32);
    VWAIT0();
    f32x4 acc = {0,0,0,0};
    #pragma unroll
    for (int kt = 0; kt < 16; ++kt)
      acc = MFMA(yb[kt], *(const s16x8*)(ywv + kt * 32), acc);
    #pragma unroll
    for (int j = 0; j < 4; ++j)
      Y[((size_t)(yrow + l4 * 4 + j) * 512 + 511) * 256 + yo] = acc[j] + ybo;
  }
}

extern "C" void kernel_launch(void* const* d_in, const int* in_sizes, int n_in,
                              void* d_out, int out_size, void* d_ws, size_t ws_size,
                              hipStream_t stream) {
  const float* x     = (const float*)d_in[0];
  const float* h0    = (const float*)d_in[1];
  const float* W_ih0 = (const float*)d_in[2];
  const float* W_hh0 = (const float*)d_in[3];
  const float* b_ih0 = (const float*)d_in[4];
  const float* b_hh0 = (const float*)d_in[5];
  const float* W_ih1 = (const float*)d_in[6];
  const float* W_hh1 = (const float*)d_in[7];
  const float* b_ih1 = (const float*)d_in[8];
  const float* b_hh1 = (const float*)d_in[9];
  const float* W_out = (const float*)d_in[10];
  const float* b_out = (const float*)d_in[11];
  float* Y = (float*)d_out;

  // ws carve: flags (32 KB) | weights | ring[2] | hlb  (~5.0 MiB)
  u32* flagsA = (u32*)d_ws;                 // 4096 u32
  u32* flagsB = flagsA + 4096;              // 4096 u32
  u16* WL0  = (u16*)(flagsA + FLAGS_U32);   // 1536*768
  u16* WL1  = WL0 + 1536 * 768;             // 2048*512
  u16* WOB  = WL1 + 2048 * 512;             // 256*512
  u16* ring = WOB + 256 * 512;              // 2 * 128*512
  u16* hlb  = ring + 2 * 65536;             // 128*512

  (void)hipFuncSetAttribute((const void*)gru_persist,
                            hipFuncAttributeMaxDynamicSharedMemorySize, LDS_BYTES);

  prep_kernel<<<dim3(1024), dim3(256), 0, stream>>>(W_ih0, W_hh0, W_ih1, W_hh1,
                                                    W_out, h0, WL0, WL1, WOB,
                                                    ring + 65536, flagsA);
  gru_persist<<<dim3(NBLK), dim3(256), LDS_BYTES, stream>>>(
      x, h0, b_ih0, b_hh0, b_ih1, b_hh1, b_out, WL0, WL1, WOB,
      ring, hlb, Y, flagsA, flagsB);
}

// Round 14
// 7041.601 us; speedup vs baseline: 2.2149x; 1.2107x over previous
//
#include <hip/hip_runtime.h>

// B=128, T=512, I=256, H=512, O=256. GRU (r,z,n), 2 layers sharing one hidden
// state (quirk), y_t = h @ W_out^T + b_out.
//
// Round 14: round-13 envelope (4 machines x 32 rows, 32 blocks each with
// weight slice in LDS, monotonic sc-flag barriers) with shorter serial chain:
//  - wave roles: w0,w1 = phase A (m-tile each), w2,w3 = phase B (m-tile each)
//    (round 13 ran both m-tiles on ONE wave while another idled)
//  - y(t-1) fused on A-waves' hb registers (blocks s<16) -> wave-2's 16 MALL
//    loads per step deleted (round-11-proven trick)
//  - poll backoff s_sleep(4) (32x32 pollers on 32 lines was congesting)
// Everything else byte-identical to the round-13 PASS.

typedef short s16x8 __attribute__((ext_vector_type(8)));  // 8 bf16
typedef float f32x4 __attribute__((ext_vector_type(4)));
typedef unsigned short u16;
typedef unsigned int u32;

#define MFMA(a, b, c) __builtin_amdgcn_mfma_f32_16x16x32_bf16((a), (b), (c), 0, 0, 0)

static constexpr int NBLK = 128;       // 4 machines x 32 slices
static constexpr int LDS_WROWS = 112;  // 48 L0h + 64 L1 rows
static constexpr int LDS_STRIDE = 520; // 512 elems + 8 pad
static constexpr int LDS_BYTES = LDS_WROWS * LDS_STRIDE * 2 + 2 * 512 * 4;
static constexpr int FLAGS_U32 = 8192;

__device__ __forceinline__ u16 f2bf(float f) {
  unsigned u = __builtin_bit_cast(unsigned, f);
  u = u + 0x7fffu + ((u >> 16) & 1u);
  return (u16)(u >> 16);
}
__device__ __forceinline__ float sigm(float x) { return 1.f / (1.f + __expf(-x)); }
__device__ __forceinline__ float tanh_f(float x) { return 1.f - 2.f / (1.f + __expf(2.f * x)); }

// ---- MALL-direct helpers (rounds 5/9/12/13 proven) ----
__device__ __forceinline__ s16x8 scload16(const u16* p) {
  s16x8 v;
  asm volatile("global_load_dwordx4 %0, %1, off sc0 sc1" : "=v"(v) : "v"(p));
  return v;  // valid only after VWAIT0()
}
__device__ __forceinline__ void scstore_u16(u16* p, u16 v) {
  unsigned vv = v;
  asm volatile("global_store_short %0, %1, off sc0 sc1" :: "v"(p), "v"(vv) : "memory");
}
#define VWAIT0()                                        \
  do {                                                  \
    asm volatile("s_waitcnt vmcnt(0)" ::: "memory");    \
    __builtin_amdgcn_sched_barrier(0);                  \
  } while (0)

// Per-machine barrier (round-13 proven; backoff bumped to sleep(4)).
__device__ __forceinline__ void fbar(u32* fbase, int s, u32 val) {
  asm volatile("s_waitcnt vmcnt(0)" ::: "memory");  // drain own data sc-stores
  __syncthreads();
  if (threadIdx.x == 0) {
    asm volatile("global_store_dword %0, %1, off sc0 sc1"
                 :: "v"(fbase + s * 32), "v"(val) : "memory");
  }
  if (threadIdx.x < 64) {
    const int lane = threadIdx.x;
    const u32* p = fbase + lane * 32;
    for (;;) {
      int ok = 1;
      if (lane < 32) {
        u32 v;
        asm volatile("global_load_dword %0, %1, off sc0 sc1\n\ts_waitcnt vmcnt(0)"
                     : "=v"(v) : "v"(p) : "memory");
        ok = (v >= val) ? 1 : 0;
      }
      if (__all(ok)) break;
      __builtin_amdgcn_s_sleep(4);
    }
  }
  __syncthreads();
}

// ---------------- weight prep + init (once per call) ----------------
__global__ void prep_kernel(const float* __restrict__ W_ih0, const float* __restrict__ W_hh0,
                            const float* __restrict__ W_ih1, const float* __restrict__ W_hh1,
                            const float* __restrict__ W_out, const float* __restrict__ h0,
                            u16* __restrict__ WL0, u16* __restrict__ WL1,
                            u16* __restrict__ WOB, u16* __restrict__ ring1,
                            u32* __restrict__ flags) {
  const int n0 = 1536 * 768, n1 = 2048 * 512, n2 = 256 * 512, n3 = 128 * 512;
  const int total = n0 + n1 + n2 + n3 + FLAGS_U32;
  for (int i = blockIdx.x * blockDim.x + threadIdx.x; i < total; i += gridDim.x * blockDim.x) {
    if (i < n0) {
      int row = i / 768, c = i % 768;
      float v = (c < 256) ? W_ih0[row * 256 + c] : W_hh0[row * 512 + (c - 256)];
      WL0[i] = f2bf(v);
    } else if (i < n0 + n1) {
      int k2 = i - n0;
      int row = k2 / 512, k = k2 % 512;
      int strip = row >> 9, j = row & 511;
      float v;
      if (strip == 0)      v = W_ih1[j * 512 + k] + W_hh1[j * 512 + k];
      else if (strip == 1) v = W_ih1[(512 + j) * 512 + k] + W_hh1[(512 + j) * 512 + k];
      else if (strip == 2) v = W_ih1[(1024 + j) * 512 + k];
      else                 v = W_hh1[(1024 + j) * 512 + k];
      WL1[k2] = f2bf(v);
    } else if (i < n0 + n1 + n2) {
      int k2 = i - n0 - n1;
      WOB[k2] = f2bf(W_out[k2]);
    } else if (i < n0 + n1 + n2 + n3) {
      int k2 = i - n0 - n1 - n2;
      ring1[k2] = f2bf(h0[k2]);     // ring[1] = h(-1) = h0
    } else {
      flags[i - n0 - n1 - n2 - n3] = 0u;
    }
  }
}

// ---------------- persistent GRU kernel (128 blocks x 256 thr) ---------------
__global__ __launch_bounds__(256) void gru_persist(
    const float* __restrict__ x, const float* __restrict__ h0,
    const float* __restrict__ b_ih0, const float* __restrict__ b_hh0,
    const float* __restrict__ b_ih1, const float* __restrict__ b_hh1,
    const float* __restrict__ b_out,
    const u16* __restrict__ WL0, const u16* __restrict__ WL1, const u16* __restrict__ WOB,
    u16* __restrict__ ring,      // [2][128][512] bf16
    u16* __restrict__ hlb,       // [128][512] bf16
    float* __restrict__ Y, u32* __restrict__ flagsA, u32* __restrict__ flagsB) {
  extern __shared__ u16 smem[];
  float* h_f32  = (float*)(smem + LDS_WROWS * LDS_STRIDE);  // [32][16]
  float* hl_f32 = h_f32 + 512;                              // [32][16]

  const int blk = blockIdx.x;
  const int m = blk >> 5;       // machine 0..3 (rows 32m..32m+31)
  const int s = blk & 31;       // hidden-col slice (cols s*16..s*16+15)
  const int w = threadIdx.x >> 6, l = threadIdx.x & 63;
  const int l15 = l & 15, l4 = l >> 4;

  // ---- init: weight slice -> LDS (identical to round 13) ----
  for (int idx = threadIdx.x; idx < LDS_WROWS * 512; idx += 256) {
    int row = idx >> 9, k = idx & 511;
    u16 v;
    if (row < 48) {
      int g = row >> 4, jj = row & 15;
      v = WL0[(size_t)(g * 512 + s * 16 + jj) * 768 + 256 + k];
    } else {
      int rr = row - 48, g = rr >> 4, jj = rr & 15;
      v = WL1[(size_t)(g * 512 + s * 16 + jj) * 512 + k];
    }
    smem[row * LDS_STRIDE + k] = v;
  }
  for (int idx = threadIdx.x; idx < 512; idx += 256) {
    int rr = idx >> 4, cc = idx & 15;
    h_f32[idx] = h0[(size_t)(32 * m + rr) * 512 + s * 16 + cc];
  }
  __syncthreads();

  const int jg = s * 16 + l15;
  const float br0 = b_ih0[jg] + b_hh0[jg];
  const float bz0 = b_ih0[512 + jg] + b_hh0[512 + jg];
  const float bni0 = b_ih0[1024 + jg], bnh0 = b_hh0[1024 + jg];
  const float br1 = b_ih1[jg] + b_hh1[jg];
  const float bz1 = b_ih1[512 + jg] + b_hh1[512 + jg];
  const float bni1 = b_ih1[1024 + jg], bnh1 = b_hh1[1024 + jg];

  const u16* wxr = WL0 + (size_t)jg * 768 + l4 * 8;
  const u16* wxz = WL0 + (size_t)(512 + jg) * 768 + l4 * 8;
  const u16* wxn = WL0 + (size_t)(1024 + jg) * 768 + l4 * 8;
  const u16* lr  = smem + (0 * 16 + l15) * LDS_STRIDE + l4 * 8;
  const u16* lz  = smem + (1 * 16 + l15) * LDS_STRIDE + l4 * 8;
  const u16* ln  = smem + (2 * 16 + l15) * LDS_STRIDE + l4 * 8;
  const u16* m10 = smem + (48 + 0 * 16 + l15) * LDS_STRIDE + l4 * 8;
  const u16* m11 = smem + (48 + 1 * 16 + l15) * LDS_STRIDE + l4 * 8;
  const u16* m12 = smem + (48 + 2 * 16 + l15) * LDS_STRIDE + l4 * 8;
  const u16* m13 = smem + (48 + 3 * 16 + l15) * LDS_STRIDE + l4 * 8;

  // A-wave (w<2) row bases; B-wave (w>=2) row bases
  const int amt = w & 1;                     // m-tile for A-waves (w0->0, w1->1)
  const int bmt = (w - 2) & 1;               // m-tile for B-waves
  const int arow = 32 * m + amt * 16 + l15;  // global A-frag row (phase A)
  const int brow = 32 * m + bmt * 16 + l15;  // global A-frag row (phase B)

  // y mapping: A-waves of blocks s<16; col-tile s, rows = own m-tile
  const int yo = (s & 15) * 16 + l15;
  const float ybo = b_out[yo];
  const u16* ywv = WOB + (size_t)yo * 512 + l4 * 8;

  u32* fA = flagsA + m * 1024;
  u32* fB = flagsB + m * 1024;

  for (int t = 0; t < 512; ++t) {
    const u16* ringc = ring + (size_t)((t + 1) & 1) * 65536;  // h(t-1)
    u16* ringn = ring + (size_t)(t & 1) * 65536;              // h(t) dest

    if (w < 2) {
      // ---- phase A: L0, one m-tile. h-loads first; x-part hides the RT ----
      s16x8 hb[16];
      const u16* hr = ringc + (size_t)arow * 512 + l4 * 8;
      #pragma unroll
      for (int kt = 0; kt < 16; ++kt) hb[kt] = scload16(hr + kt * 32);

      f32x4 aR = {0,0,0,0}, aZ = {0,0,0,0}, aNI = {0,0,0,0}, aNH = {0,0,0,0};
      const float* xr = x + ((size_t)arow * 512 + t) * 256 + l4 * 8;
      #pragma unroll
      for (int kt = 0; kt < 8; ++kt) {
        float4 u = *(const float4*)(xr + kt * 32);
        float4 v = *(const float4*)(xr + kt * 32 + 4);
        s16x8 a;
        a[0]=f2bf(u.x); a[1]=f2bf(u.y); a[2]=f2bf(u.z); a[3]=f2bf(u.w);
        a[4]=f2bf(v.x); a[5]=f2bf(v.y); a[6]=f2bf(v.z); a[7]=f2bf(v.w);
        aR  = MFMA(a, *(const s16x8*)(wxr + kt * 32), aR);
        aZ  = MFMA(a, *(const s16x8*)(wxz + kt * 32), aZ);
        aNI = MFMA(a, *(const s16x8*)(wxn + kt * 32), aNI);
      }
      VWAIT0();
      #pragma unroll
      for (int kt = 0; kt < 16; ++kt) {
        aR  = MFMA(hb[kt], *(const s16x8*)(lr + kt * 32), aR);
        aZ  = MFMA(hb[kt], *(const s16x8*)(lz + kt * 32), aZ);
        aNH = MFMA(hb[kt], *(const s16x8*)(ln + kt * 32), aNH);
      }

      // ---- fused y(t-1) from hb registers (blocks s<16) ----
      if (s < 16 && t > 0) {
        f32x4 acc = {0,0,0,0};
        #pragma unroll
        for (int kt = 0; kt < 16; ++kt)
          acc = MFMA(hb[kt], *(const s16x8*)(ywv + kt * 32), acc);
        #pragma unroll
        for (int j = 0; j < 4; ++j)
          Y[((size_t)(32 * m + amt * 16 + l4 * 4 + j) * 512 + (t - 1)) * 256 + yo]
              = acc[j] + ybo;
      }

      // ---- L0 epilogue ----
      #pragma unroll
      for (int j = 0; j < 4; ++j) {
        int rr = amt * 16 + l4 * 4 + j;
        float r = sigm(aR[j] + br0), z = sigm(aZ[j] + bz0);
        float n = tanh_f(aNI[j] + bni0 + r * (aNH[j] + bnh0));
        float h = (1.f - z) * n + z * h_f32[rr * 16 + l15];
        hl_f32[rr * 16 + l15] = h;
        scstore_u16(hlb + (size_t)(32 * m + rr) * 512 + jg, f2bf(h));
      }
    }
    fbar(fA, s, (u32)(t + 1));

    if (w >= 2) {
      // ---- phase B: L1, one m-tile (input == hidden == h_l0) ----
      s16x8 pb[16];
      const u16* ar = hlb + (size_t)brow * 512 + l4 * 8;
      #pragma unroll
      for (int kt = 0; kt < 16; ++kt) pb[kt] = scload16(ar + kt * 32);
      VWAIT0();
      f32x4 cR = {0,0,0,0}, cZ = {0,0,0,0}, cNI = {0,0,0,0}, cNH = {0,0,0,0};
      #pragma unroll
      for (int kt = 0; kt < 16; ++kt) {
        cR  = MFMA(pb[kt], *(const s16x8*)(m10 + kt * 32), cR);
        cZ  = MFMA(pb[kt], *(const s16x8*)(m11 + kt * 32), cZ);
        cNI = MFMA(pb[kt], *(const s16x8*)(m12 + kt * 32), cNI);
        cNH = MFMA(pb[kt], *(const s16x8*)(m13 + kt * 32), cNH);
      }
      #pragma unroll
      for (int j = 0; j < 4; ++j) {
        int rr = bmt * 16 + l4 * 4 + j;
        float r = sigm(cR[j] + br1), z = sigm(cZ[j] + bz1);
        float n = tanh_f(cNI[j] + bni1 + r * (cNH[j] + bnh1));
        float h = (1.f - z) * n + z * hl_f32[rr * 16 + l15];
        h_f32[rr * 16 + l15] = h;
        scstore_u16(ringn + (size_t)(32 * m + rr) * 512 + jg, f2bf(h));
      }
    }
    fbar(fB, s, (u32)(t + 1));
  }

  // ---- final y (t = 511): h(511) is in ring[1] ----
  if (w < 2 && s < 16) {
    const u16* Hf = ring + 65536;
    s16x8 yb[16];
    const u16* ar = Hf + (size_t)arow * 512 + l4 * 8;
    #pragma unroll
    for (int kt = 0; kt < 16; ++kt) yb[kt] = scload16(ar + kt * 32);
    VWAIT0();
    f32x4 acc = {0,0,0,0};
    #pragma unroll
    for (int kt = 0; kt < 16; ++kt)
      acc = MFMA(yb[kt], *(const s16x8*)(ywv + kt * 32), acc);
    #pragma unroll
    for (int j = 0; j < 4; ++j)
      Y[((size_t)(32 * m + amt * 16 + l4 * 4 + j) * 512 + 511) * 256 + yo]
          = acc[j] + ybo;
  }
}

extern "C" void kernel_launch(void* const* d_in, const int* in_sizes, int n_in,
                              void* d_out, int out_size, void* d_ws, size_t ws_size,
                              hipStream_t stream) {
  const float* x     = (const float*)d_in[0];
  const float* h0    = (const float*)d_in[1];
  const float* W_ih0 = (const float*)d_in[2];
  const float* W_hh0 = (const float*)d_in[3];
  const float* b_ih0 = (const float*)d_in[4];
  const float* b_hh0 = (const float*)d_in[5];
  const float* W_ih1 = (const float*)d_in[6];
  const float* W_hh1 = (const float*)d_in[7];
  const float* b_ih1 = (const float*)d_in[8];
  const float* b_hh1 = (const float*)d_in[9];
  const float* W_out = (const float*)d_in[10];
  const float* b_out = (const float*)d_in[11];
  float* Y = (float*)d_out;

  // ws carve: flags (32 KB) | weights | ring[2] | hlb  (~5.0 MiB)
  u32* flagsA = (u32*)d_ws;
  u32* flagsB = flagsA + 4096;
  u16* WL0  = (u16*)(flagsA + FLAGS_U32);
  u16* WL1  = WL0 + 1536 * 768;
  u16* WOB  = WL1 + 2048 * 512;
  u16* ring = WOB + 256 * 512;
  u16* hlb  = ring + 2 * 65536;

  (void)hipFuncSetAttribute((const void*)gru_persist,
                            hipFuncAttributeMaxDynamicSharedMemorySize, LDS_BYTES);

  prep_kernel<<<dim3(1024), dim3(256), 0, stream>>>(W_ih0, W_hh0, W_ih1, W_hh1,
                                                    W_out, h0, WL0, WL1, WOB,
                                                    ring + 65536, flagsA);
  gru_persist<<<dim3(NBLK), dim3(256), LDS_BYTES, stream>>>(
      x, h0, b_ih0, b_hh0, b_ih1, b_hh1, b_out, WL0, WL1, WOB,
      ring, hlb, Y, flagsA, flagsB);
}

// Round 15
// 5642.018 us; speedup vs baseline: 2.7644x; 1.2481x over previous
//
#include <hip/hip_runtime.h>

// B=128, T=512, I=256, H=512, O=256. GRU (r,z,n), 2 layers sharing one hidden
// state (quirk), y_t = h @ W_out^T + b_out.
//
// Round 15: round-14 envelope (4 machines x 32 rows; 32 blocks/machine with
// weight slice in LDS; w0,w1 = phase A m-tiles, w2,w3 = phase B m-tiles;
// f32 carries in LDS; MALL sc0|sc1 exchange; monotonic flags) with
// WAVE-DECOUPLED sync (no __syncthreads in the t-loop):
//  - 64 arrival lines/machine/phase (one per writer wave; 1 store, 0 sharing)
//  - block s=0's waves gather (64 lanes x 1 line each); w0/w2 publish 8
//    go-lines; workers poll their go-line (<=8 readers/line, backoff)
//  - y(t-1) deferred until after the fA flag store (off the critical path)
// Flag-ordered LDS carries: every cross-wave LDS read is ordered by a flag
// stored after a vmcnt(0)+lgkmcnt(0) drain. Monotonic values -> no resets,
// deadlock-free (all 128 blocks resident at 1 block/CU).

typedef short s16x8 __attribute__((ext_vector_type(8)));  // 8 bf16
typedef float f32x4 __attribute__((ext_vector_type(4)));
typedef unsigned short u16;
typedef unsigned int u32;

#define MFMA(a, b, c) __builtin_amdgcn_mfma_f32_16x16x32_bf16((a), (b), (c), 0, 0, 0)

static constexpr int NBLK = 128;       // 4 machines x 32 slices
static constexpr int LDS_WROWS = 112;  // 48 L0h + 64 L1 rows
static constexpr int LDS_STRIDE = 520; // 512 elems + 8 pad
static constexpr int LDS_BYTES = LDS_WROWS * LDS_STRIDE * 2 + 2 * 512 * 4;
// flag region (u32): FA[4][64][32] | FB[4][64][32] | GA[4][8][32] | GB[4][8][32]
static constexpr int OFF_FA = 0, OFF_FB = 8192, OFF_GA = 16384, OFF_GB = 17408;
static constexpr int FLAGS_U32 = 18432;

__device__ __forceinline__ u16 f2bf(float f) {
  unsigned u = __builtin_bit_cast(unsigned, f);
  u = u + 0x7fffu + ((u >> 16) & 1u);
  return (u16)(u >> 16);
}
__device__ __forceinline__ float sigm(float x) { return 1.f / (1.f + __expf(-x)); }
__device__ __forceinline__ float tanh_f(float x) { return 1.f - 2.f / (1.f + __expf(2.f * x)); }

// ---- MALL-direct helpers (rounds 5/9/12/13/14 proven) ----
__device__ __forceinline__ s16x8 scload16(const u16* p) {
  s16x8 v;
  asm volatile("global_load_dwordx4 %0, %1, off sc0 sc1" : "=v"(v) : "v"(p));
  return v;  // valid only after VWAIT0()
}
__device__ __forceinline__ void scstore_u16(u16* p, u16 v) {
  unsigned vv = v;
  asm volatile("global_store_short %0, %1, off sc0 sc1" :: "v"(p), "v"(vv) : "memory");
}
__device__ __forceinline__ u32 scload_u32(const u32* p) {
  u32 v;
  asm volatile("global_load_dword %0, %1, off sc0 sc1\n\ts_waitcnt vmcnt(0)"
               : "=v"(v) : "v"(p) : "memory");
  return v;
}
__device__ __forceinline__ void scstore_u32(u32* p, u32 v) {
  asm volatile("global_store_dword %0, %1, off sc0 sc1" :: "v"(p), "v"(v) : "memory");
}
#define VWAIT0()                                        \
  do {                                                  \
    asm volatile("s_waitcnt vmcnt(0)" ::: "memory");    \
    __builtin_amdgcn_sched_barrier(0);                  \
  } while (0)
#define DRAIN_ALL()                                              \
  do {                                                           \
    asm volatile("s_waitcnt vmcnt(0) lgkmcnt(0)" ::: "memory");  \
    __builtin_amdgcn_sched_barrier(0);                           \
  } while (0)

// Lead gather: 64 lanes watch 64 arrival lines (1 reader/line).
__device__ __forceinline__ void gather64(const u32* base, u32 val, int l) {
  for (;;) {
    u32 v = scload_u32(base + l * 32);
    if (__all(v >= val)) break;
    __builtin_amdgcn_s_sleep(2);
  }
}
// Worker poll: all lanes watch one go-line (uniform value).
__device__ __forceinline__ void pollgo(const u32* p, u32 val) {
  for (;;) {
    u32 v = scload_u32(p);
    if (v >= val) break;
    __builtin_amdgcn_s_sleep(4);
  }
}

// ---------------- weight prep + init (once per call) ----------------
__global__ void prep_kernel(const float* __restrict__ W_ih0, const float* __restrict__ W_hh0,
                            const float* __restrict__ W_ih1, const float* __restrict__ W_hh1,
                            const float* __restrict__ W_out, const float* __restrict__ h0,
                            u16* __restrict__ WL0, u16* __restrict__ WL1,
                            u16* __restrict__ WOB, u16* __restrict__ ring1,
                            u32* __restrict__ flags) {
  const int n0 = 1536 * 768, n1 = 2048 * 512, n2 = 256 * 512, n3 = 128 * 512;
  const int total = n0 + n1 + n2 + n3 + FLAGS_U32;
  for (int i = blockIdx.x * blockDim.x + threadIdx.x; i < total; i += gridDim.x * blockDim.x) {
    if (i < n0) {
      int row = i / 768, c = i % 768;
      float v = (c < 256) ? W_ih0[row * 256 + c] : W_hh0[row * 512 + (c - 256)];
      WL0[i] = f2bf(v);
    } else if (i < n0 + n1) {
      int k2 = i - n0;
      int row = k2 / 512, k = k2 % 512;
      int strip = row >> 9, j = row & 511;
      float v;
      if (strip == 0)      v = W_ih1[j * 512 + k] + W_hh1[j * 512 + k];
      else if (strip == 1) v = W_ih1[(512 + j) * 512 + k] + W_hh1[(512 + j) * 512 + k];
      else if (strip == 2) v = W_ih1[(1024 + j) * 512 + k];
      else                 v = W_hh1[(1024 + j) * 512 + k];
      WL1[k2] = f2bf(v);
    } else if (i < n0 + n1 + n2) {
      int k2 = i - n0 - n1;
      WOB[k2] = f2bf(W_out[k2]);
    } else if (i < n0 + n1 + n2 + n3) {
      int k2 = i - n0 - n1 - n2;
      ring1[k2] = f2bf(h0[k2]);     // ring[1] = h(-1) = h0
    } else {
      flags[i - n0 - n1 - n2 - n3] = 0u;
    }
  }
}

// ---------------- persistent GRU kernel (128 blocks x 256 thr) ---------------
__global__ __launch_bounds__(256) void gru_persist(
    const float* __restrict__ x, const float* __restrict__ h0,
    const float* __restrict__ b_ih0, const float* __restrict__ b_hh0,
    const float* __restrict__ b_ih1, const float* __restrict__ b_hh1,
    const float* __restrict__ b_out,
    const u16* __restrict__ WL0, const u16* __restrict__ WL1, const u16* __restrict__ WOB,
    u16* __restrict__ ring,      // [2][128][512] bf16
    u16* __restrict__ hlb,       // [128][512] bf16
    float* __restrict__ Y, u32* __restrict__ flags) {
  extern __shared__ u16 smem[];
  float* h_f32  = (float*)(smem + LDS_WROWS * LDS_STRIDE);  // [32][16]
  float* hl_f32 = h_f32 + 512;                              // [32][16]

  const int blk = blockIdx.x;
  const int m = blk >> 5;       // machine 0..3 (rows 32m..32m+31)
  const int s = blk & 31;       // hidden-col slice (cols s*16..s*16+15)
  const int w = threadIdx.x >> 6, l = threadIdx.x & 63;
  const int l15 = l & 15, l4 = l >> 4;

  // ---- init: weight slice -> LDS (identical to rounds 13/14) ----
  for (int idx = threadIdx.x; idx < LDS_WROWS * 512; idx += 256) {
    int row = idx >> 9, k = idx & 511;
    u16 v;
    if (row < 48) {
      int g = row >> 4, jj = row & 15;
      v = WL0[(size_t)(g * 512 + s * 16 + jj) * 768 + 256 + k];
    } else {
      int rr = row - 48, g = rr >> 4, jj = rr & 15;
      v = WL1[(size_t)(g * 512 + s * 16 + jj) * 512 + k];
    }
    smem[row * LDS_STRIDE + k] = v;
  }
  for (int idx = threadIdx.x; idx < 512; idx += 256) {
    int rr = idx >> 4, cc = idx & 15;
    h_f32[idx] = h0[(size_t)(32 * m + rr) * 512 + s * 16 + cc];
  }
  __syncthreads();

  const int jg = s * 16 + l15;
  const float br0 = b_ih0[jg] + b_hh0[jg];
  const float bz0 = b_ih0[512 + jg] + b_hh0[512 + jg];
  const float bni0 = b_ih0[1024 + jg], bnh0 = b_hh0[1024 + jg];
  const float br1 = b_ih1[jg] + b_hh1[jg];
  const float bz1 = b_ih1[512 + jg] + b_hh1[512 + jg];
  const float bni1 = b_ih1[1024 + jg], bnh1 = b_hh1[1024 + jg];

  const u16* wxr = WL0 + (size_t)jg * 768 + l4 * 8;
  const u16* wxz = WL0 + (size_t)(512 + jg) * 768 + l4 * 8;
  const u16* wxn = WL0 + (size_t)(1024 + jg) * 768 + l4 * 8;
  const u16* lr  = smem + (0 * 16 + l15) * LDS_STRIDE + l4 * 8;
  const u16* lz  = smem + (1 * 16 + l15) * LDS_STRIDE + l4 * 8;
  const u16* ln  = smem + (2 * 16 + l15) * LDS_STRIDE + l4 * 8;
  const u16* m10 = smem + (48 + 0 * 16 + l15) * LDS_STRIDE + l4 * 8;
  const u16* m11 = smem + (48 + 1 * 16 + l15) * LDS_STRIDE + l4 * 8;
  const u16* m12 = smem + (48 + 2 * 16 + l15) * LDS_STRIDE + l4 * 8;
  const u16* m13 = smem + (48 + 3 * 16 + l15) * LDS_STRIDE + l4 * 8;

  // machine's flag sub-regions
  u32* fA = flags + OFF_FA + m * 2048;   // 64 arrival lines (A)
  u32* fB = flags + OFF_FB + m * 2048;   // 64 arrival lines (B)
  u32* gA = flags + OFF_GA + m * 256;    // 8 go-lines (A done)
  u32* gB = flags + OFF_GB + m * 256;    // 8 go-lines (B done)

  if (w < 2) {
    // ================= A-waves (layer 0 + fused y) =================
    const int amt = w;
    const int arow = 32 * m + amt * 16 + l15;
    u32* myfA = fA + (s * 2 + amt) * 32;
    const u32* mygo = gB + (s & 7) * 32;
    const int yo = (s & 15) * 16 + l15;
    const float ybo = b_out[yo];
    const u16* ywv = WOB + (size_t)yo * 512 + l4 * 8;

    for (int t = 0; t < 512; ++t) {
      const u16* ringc = ring + (size_t)((t + 1) & 1) * 65536;  // h(t-1)

      // ---- wait: B(t-1) globally done ----
      if (t > 0) {
        if (s == 0) {
          gather64(fB, (u32)t, l);
          if (w == 0 && l < 8) scstore_u32(gB + l * 32, (u32)t);
        } else {
          pollgo(mygo, (u32)t);
        }
        __builtin_amdgcn_sched_barrier(0);
      }

      // ---- h-loads first; x-MFMA hides the RT ----
      s16x8 hb[16];
      const u16* hr = ringc + (size_t)arow * 512 + l4 * 8;
      #pragma unroll
      for (int kt = 0; kt < 16; ++kt) hb[kt] = scload16(hr + kt * 32);

      f32x4 aR = {0,0,0,0}, aZ = {0,0,0,0}, aNI = {0,0,0,0}, aNH = {0,0,0,0};
      const float* xr = x + ((size_t)arow * 512 + t) * 256 + l4 * 8;
      #pragma unroll
      for (int kt = 0; kt < 8; ++kt) {
        float4 u = *(const float4*)(xr + kt * 32);
        float4 v = *(const float4*)(xr + kt * 32 + 4);
        s16x8 a;
        a[0]=f2bf(u.x); a[1]=f2bf(u.y); a[2]=f2bf(u.z); a[3]=f2bf(u.w);
        a[4]=f2bf(v.x); a[5]=f2bf(v.y); a[6]=f2bf(v.z); a[7]=f2bf(v.w);
        aR  = MFMA(a, *(const s16x8*)(wxr + kt * 32), aR);
        aZ  = MFMA(a, *(const s16x8*)(wxz + kt * 32), aZ);
        aNI = MFMA(a, *(const s16x8*)(wxn + kt * 32), aNI);
      }
      VWAIT0();
      #pragma unroll
      for (int kt = 0; kt < 16; ++kt) {
        aR  = MFMA(hb[kt], *(const s16x8*)(lr + kt * 32), aR);
        aZ  = MFMA(hb[kt], *(const s16x8*)(lz + kt * 32), aZ);
        aNH = MFMA(hb[kt], *(const s16x8*)(ln + kt * 32), aNH);
      }

      // ---- L0 epilogue: carries + hlb stores ----
      #pragma unroll
      for (int j = 0; j < 4; ++j) {
        int rr = amt * 16 + l4 * 4 + j;
        float r = sigm(aR[j] + br0), z = sigm(aZ[j] + bz0);
        float n = tanh_f(aNI[j] + bni0 + r * (aNH[j] + bnh0));
        float h = (1.f - z) * n + z * h_f32[rr * 16 + l15];
        hl_f32[rr * 16 + l15] = h;
        scstore_u16(hlb + (size_t)(32 * m + rr) * 512 + jg, f2bf(h));
      }
      DRAIN_ALL();
      if (l == 0) scstore_u32(myfA, (u32)(t + 1));

      // ---- deferred y(t-1) from hb registers (hidden under phase B) ----
      if (s < 16 && t > 0) {
        f32x4 acc = {0,0,0,0};
        #pragma unroll
        for (int kt = 0; kt < 16; ++kt)
          acc = MFMA(hb[kt], *(const s16x8*)(ywv + kt * 32), acc);
        #pragma unroll
        for (int j = 0; j < 4; ++j)
          Y[((size_t)(32 * m + amt * 16 + l4 * 4 + j) * 512 + (t - 1)) * 256 + yo]
              = acc[j] + ybo;
      }
    }

    // ---- final y(511): wait B(511), then read ring[1] ----
    if (s == 0) {
      gather64(fB, 512u, l);
      if (w == 0 && l < 8) scstore_u32(gB + l * 32, 512u);
    } else {
      pollgo(mygo, 512u);
    }
    if (s < 16) {
      const u16* Hf = ring + 65536;
      s16x8 yb[16];
      const u16* ar = Hf + (size_t)arow * 512 + l4 * 8;
      #pragma unroll
      for (int kt = 0; kt < 16; ++kt) yb[kt] = scload16(ar + kt * 32);
      VWAIT0();
      f32x4 acc = {0,0,0,0};
      #pragma unroll
      for (int kt = 0; kt < 16; ++kt)
        acc = MFMA(yb[kt], *(const s16x8*)(ywv + kt * 32), acc);
      #pragma unroll
      for (int j = 0; j < 4; ++j)
        Y[((size_t)(32 * m + amt * 16 + l4 * 4 + j) * 512 + 511) * 256 + yo]
            = acc[j] + ybo;
    }
  } else {
    // ================= B-waves (layer 1) =================
    const int bmt = w - 2;
    const int brow = 32 * m + bmt * 16 + l15;
    u32* myfB = fB + (s * 2 + bmt) * 32;
    const u32* mygo = gA + (s & 7) * 32;

    for (int t = 0; t < 512; ++t) {
      u16* ringn = ring + (size_t)(t & 1) * 65536;  // h(t) dest

      // ---- wait: A(t) globally done ----
      if (s == 0) {
        gather64(fA, (u32)(t + 1), l);
        if (w == 2 && l < 8) scstore_u32(gA + l * 32, (u32)(t + 1));
      } else {
        pollgo(mygo, (u32)(t + 1));
      }
      __builtin_amdgcn_sched_barrier(0);

      // ---- load h_l0, MFMA ----
      s16x8 pb[16];
      const u16* ar = hlb + (size_t)brow * 512 + l4 * 8;
      #pragma unroll
      for (int kt = 0; kt < 16; ++kt) pb[kt] = scload16(ar + kt * 32);
      VWAIT0();
      f32x4 cR = {0,0,0,0}, cZ = {0,0,0,0}, cNI = {0,0,0,0}, cNH = {0,0,0,0};
      #pragma unroll
      for (int kt = 0; kt < 16; ++kt) {
        cR  = MFMA(pb[kt], *(const s16x8*)(m10 + kt * 32), cR);
        cZ  = MFMA(pb[kt], *(const s16x8*)(m11 + kt * 32), cZ);
        cNI = MFMA(pb[kt], *(const s16x8*)(m12 + kt * 32), cNI);
        cNH = MFMA(pb[kt], *(const s16x8*)(m13 + kt * 32), cNH);
      }
      #pragma unroll
      for (int j = 0; j < 4; ++j) {
        int rr = bmt * 16 + l4 * 4 + j;
        float r = sigm(cR[j] + br1), z = sigm(cZ[j] + bz1);
        float n = tanh_f(cNI[j] + bni1 + r * (cNH[j] + bnh1));
        float h = (1.f - z) * n + z * hl_f32[rr * 16 + l15];
        h_f32[rr * 16 + l15] = h;
        scstore_u16(ringn + (size_t)(32 * m + rr) * 512 + jg, f2bf(h));
      }
      DRAIN_ALL();
      if (l == 0) scstore_u32(myfB, (u32)(t + 1));
    }
  }
}

extern "C" void kernel_launch(void* const* d_in, const int* in_sizes, int n_in,
                              void* d_out, int out_size, void* d_ws, size_t ws_size,
                              hipStream_t stream) {
  const float* x     = (const float*)d_in[0];
  const float* h0    = (const float*)d_in[1];
  const float* W_ih0 = (const float*)d_in[2];
  const float* W_hh0 = (const float*)d_in[3];
  const float* b_ih0 = (const float*)d_in[4];
  const float* b_hh0 = (const float*)d_in[5];
  const float* W_ih1 = (const float*)d_in[6];
  const float* W_hh1 = (const float*)d_in[7];
  const float* b_ih1 = (const float*)d_in[8];
  const float* b_hh1 = (const float*)d_in[9];
  const float* W_out = (const float*)d_in[10];
  const float* b_out = (const float*)d_in[11];
  float* Y = (float*)d_out;

  // ws carve: flags (72 KB) | weights | ring[2] | hlb  (~5.0 MiB)
  u32* flags = (u32*)d_ws;
  u16* WL0  = (u16*)(flags + FLAGS_U32);
  u16* WL1  = WL0 + 1536 * 768;
  u16* WOB  = WL1 + 2048 * 512;
  u16* ring = WOB + 256 * 512;
  u16* hlb  = ring + 2 * 65536;

  (void)hipFuncSetAttribute((const void*)gru_persist,
                            hipFuncAttributeMaxDynamicSharedMemorySize, LDS_BYTES);

  prep_kernel<<<dim3(1024), dim3(256), 0, stream>>>(W_ih0, W_hh0, W_ih1, W_hh1,
                                                    W_out, h0, WL0, WL1, WOB,
                                                    ring + 65536, flags);
  gru_persist<<<dim3(NBLK), dim3(256), LDS_BYTES, stream>>>(
      x, h0, b_ih0, b_hh0, b_ih1, b_hh1, b_out, WL0, WL1, WOB,
      ring, hlb, Y, flags);
}